// Round 1
// baseline (7169.032 us; speedup 1.0000x reference)
//
#include <hip/hip_runtime.h>
#include <math.h>

// AFNO2D: rfft2(128x128, ortho) -> blockdiag complex MLP (8 x 96) -> softshrink -> irfft2 -> +bias
// B=4, H=W=128, C=768. All fp32. Per-batch pipeline over two ws buffers
// (needs 4 * 6,389,760 floats = ~97.5 MiB of d_ws).

#define HD   768
#define NBLK 8
#define BLKC 96
#define HH   128
#define WW   128
#define WC   65

constexpr float SC    = 0.08838834764831845f;      // 1/sqrt(128)
constexpr float TWOPI = 6.28318530717958647692f;
constexpr size_t NPB  = (size_t)HH * WC * HD;      // per-batch plane elems (6,389,760)

// ---------------- stage 1: rfft along W (real -> 65 complex), x[b,h,w,c] -> A[h,kw,c]
__global__ __launch_bounds__(256) void k_rfft_w(const float* __restrict__ x,
                                                float* __restrict__ ore,
                                                float* __restrict__ oim, int b) {
  __shared__ float xs[WW][64];
  __shared__ float ct[128], st[128];
  const int h = blockIdx.x, c0 = blockIdx.y * 64, t = threadIdx.x;
  if (t < 128) { float s, c; sincosf((TWOPI / 128.f) * t, &s, &c); ct[t] = c; st[t] = s; }
  const float* xp = x + ((size_t)(b * HH + h)) * WW * HD + c0;
  for (int idx = t; idx < WW * 64; idx += 256) {
    int w = idx >> 6, c = idx & 63;
    xs[w][c] = xp[(size_t)w * HD + c];
  }
  __syncthreads();
  const int c = t & 63, kw0 = t >> 6;
  for (int kw = kw0; kw < WC; kw += 4) {
    float ar = 0.f, ai = 0.f;
    int idx = 0;
    for (int w = 0; w < WW; ++w) {
      float xv = xs[w][c];
      ar = fmaf(xv, ct[idx], ar);
      ai = fmaf(-xv, st[idx], ai);
      idx = (idx + kw) & 127;
    }
    size_t o = ((size_t)h * WC + kw) * HD + c0 + c;
    ore[o] = ar * SC;
    oim[o] = ai * SC;
  }
}

// ---------------- stage 2/4: complex FFT along H. SIGN=-1 forward, +1 inverse. [r,kv,c] -> [ko,kv,c]
template <int SIGN>
__global__ __launch_bounds__(256) void k_fft_h(const float* __restrict__ ire,
                                               const float* __restrict__ iim,
                                               float* __restrict__ ore,
                                               float* __restrict__ oim) {
  __shared__ float zr[128][32], zi[128][32];
  __shared__ float ct[128], st[128];
  const int kv = blockIdx.x, c0 = blockIdx.y * 32, t = threadIdx.x;
  if (t < 128) { float s, c; sincosf((TWOPI / 128.f) * t, &s, &c); ct[t] = c; st[t] = s; }
  for (int idx = t; idx < 128 * 32; idx += 256) {
    int r = idx >> 5, c = idx & 31;
    size_t g = ((size_t)r * WC + kv) * HD + c0 + c;
    zr[r][c] = ire[g];
    zi[r][c] = iim[g];
  }
  __syncthreads();
  const int c = t & 31, g0 = t >> 5;
  for (int ko = g0; ko < 128; ko += 8) {
    float ar = 0.f, ai = 0.f;
    int idx = 0;
    for (int r = 0; r < 128; ++r) {
      float cr = ct[idx], sn = st[idx];
      float vr = zr[r][c], vi = zi[r][c];
      if constexpr (SIGN < 0) {
        ar = fmaf(vr, cr, ar); ar = fmaf(vi, sn, ar);
        ai = fmaf(vi, cr, ai); ai = fmaf(-vr, sn, ai);
      } else {
        ar = fmaf(vr, cr, ar); ar = fmaf(-vi, sn, ar);
        ai = fmaf(vi, cr, ai); ai = fmaf(vr, sn, ai);
      }
      idx = (idx + ko) & 127;
    }
    size_t o = ((size_t)ko * WC + kv) * HD + c0 + c;
    ore[o] = ar * SC;
    oim[o] = ai * SC;
  }
}

// ---------------- stage 3: blockdiag complex MLP + softshrink. 16 positions x 1 channel-block per WG.
__global__ __launch_bounds__(256) void k_mlp(const float* __restrict__ ire,
                                             const float* __restrict__ iim,
                                             const float* __restrict__ w1,
                                             const float* __restrict__ b1,
                                             const float* __restrict__ w2,
                                             const float* __restrict__ b2,
                                             float* __restrict__ ore,
                                             float* __restrict__ oim) {
  __shared__ float xr_s[16][BLKC], xi_s[16][BLKC];
  __shared__ float o1r_s[16][BLKC], o1i_s[16][BLKC];
  __shared__ float wa_s[48 * BLKC], wb_s[48 * BLKC];
  const int p0 = blockIdx.x * 16, n = blockIdx.y, t = threadIdx.x;

  for (int idx = t; idx < 16 * BLKC; idx += 256) {
    int p = idx / BLKC, j = idx - p * BLKC;
    size_t g = (size_t)(p0 + p) * HD + n * BLKC + j;
    xr_s[p][j] = ire[g];
    xi_s[p][j] = iim[g];
  }

  float accR[6], accI[6];
  int pe[6], ie[6];
#pragma unroll
  for (int k = 0; k < 6; ++k) {
    int e = t + 256 * k;
    pe[k] = e / BLKC;
    ie[k] = e - pe[k] * BLKC;
    accR[k] = b1[n * BLKC + ie[k]];
    accI[k] = b1[(NBLK + n) * BLKC + ie[k]];
  }

  // layer 1: o1 = relu(xr*W10 - xi*W11 + b10 , xi*W10 + xr*W11 + b11)
  for (int jc = 0; jc < 2; ++jc) {
    __syncthreads();
    const float* wA = w1 + ((size_t)n * BLKC + jc * 48) * BLKC;
    const float* wB = w1 + ((size_t)(NBLK + n) * BLKC + jc * 48) * BLKC;
    for (int idx = t; idx < 48 * BLKC; idx += 256) { wa_s[idx] = wA[idx]; wb_s[idx] = wB[idx]; }
    __syncthreads();
    const int jb = jc * 48;
    for (int k = 0; k < 6; ++k) {
      const int p = pe[k], i = ie[k];
      float ar = accR[k], ai = accI[k];
      for (int j = 0; j < 48; ++j) {
        float xrv = xr_s[p][jb + j], xiv = xi_s[p][jb + j];
        float wa = wa_s[j * BLKC + i], wb = wb_s[j * BLKC + i];
        ar = fmaf(xrv, wa, ar); ar = fmaf(-xiv, wb, ar);
        ai = fmaf(xiv, wa, ai); ai = fmaf(xrv, wb, ai);
      }
      accR[k] = ar; accI[k] = ai;
    }
  }
  __syncthreads();
#pragma unroll
  for (int k = 0; k < 6; ++k) {
    o1r_s[pe[k]][ie[k]] = fmaxf(accR[k], 0.f);
    o1i_s[pe[k]][ie[k]] = fmaxf(accI[k], 0.f);
    accR[k] = b2[n * BLKC + ie[k]];
    accI[k] = b2[(NBLK + n) * BLKC + ie[k]];
  }
  // layer 2
  for (int jc = 0; jc < 2; ++jc) {
    __syncthreads();
    const float* wA = w2 + ((size_t)n * BLKC + jc * 48) * BLKC;
    const float* wB = w2 + ((size_t)(NBLK + n) * BLKC + jc * 48) * BLKC;
    for (int idx = t; idx < 48 * BLKC; idx += 256) { wa_s[idx] = wA[idx]; wb_s[idx] = wB[idx]; }
    __syncthreads();
    const int jb = jc * 48;
    for (int k = 0; k < 6; ++k) {
      const int p = pe[k], i = ie[k];
      float ar = accR[k], ai = accI[k];
      for (int j = 0; j < 48; ++j) {
        float vr = o1r_s[p][jb + j], vi = o1i_s[p][jb + j];
        float wa = wa_s[j * BLKC + i], wb = wb_s[j * BLKC + i];
        ar = fmaf(vr, wa, ar); ar = fmaf(-vi, wb, ar);
        ai = fmaf(vi, wa, ai); ai = fmaf(vr, wb, ai);
      }
      accR[k] = ar; accI[k] = ai;
    }
  }
  // softshrink + store
#pragma unroll
  for (int k = 0; k < 6; ++k) {
    int pl = p0 + pe[k];
    int ku = pl / WC, kv = pl - ku * WC;
    float kus = (ku >= 64) ? (float)(ku - 128) : (float)ku;
    float k2 = kus * kus + (float)(kv * kv);
    float thr = fmaxf(0.01f * expf(-0.00125f * k2), 0.0005f);  // -0.5/400
    float mr = accR[k], mi = accI[k];
    float mag = sqrtf(mr * mr + mi * mi + 1e-8f);
    float sf = fmaxf(mag - thr, 0.f) / mag;
    size_t g = (size_t)pl * HD + n * BLKC + ie[k];
    ore[g] = mr * sf;
    oim[g] = mi * sf;
  }
}

// ---------------- stage 5: irfft along W (ignores imag of bins 0 and 64, numpy c2r semantics) + bias
__global__ __launch_bounds__(256) void k_irfft_w(const float* __restrict__ ire,
                                                 const float* __restrict__ iim,
                                                 const float* __restrict__ x,
                                                 float* __restrict__ out, int b) {
  __shared__ float zr[WC][64], zi[WC][64];
  __shared__ float ct[128], st[128];
  const int h = blockIdx.x, c0 = blockIdx.y * 64, t = threadIdx.x;
  if (t < 128) { float s, c; sincosf((TWOPI / 128.f) * t, &s, &c); ct[t] = c; st[t] = s; }
  for (int idx = t; idx < WC * 64; idx += 256) {
    int kv = idx >> 6, c = idx & 63;
    size_t g = ((size_t)h * WC + kv) * HD + c0 + c;
    zr[kv][c] = ire[g];
    zi[kv][c] = iim[g];
  }
  __syncthreads();
  const int c = t & 63, w0 = t >> 6;
  for (int w = w0; w < WW; w += 4) {
    float acc = zr[0][c] + ((w & 1) ? -zr[64][c] : zr[64][c]);
    int idx = w;
    for (int k = 1; k < 64; ++k) {
      acc += 2.f * fmaf(zr[k][c], ct[idx], -zi[k][c] * st[idx]);
      idx = (idx + w) & 127;
    }
    size_t go = (((size_t)(b * HH + h)) * WW + w) * HD + c0 + c;
    out[go] = fmaf(acc, SC, x[go]);
  }
}

extern "C" void kernel_launch(void* const* d_in, const int* in_sizes, int n_in,
                              void* d_out, int out_size, void* d_ws, size_t ws_size,
                              hipStream_t stream) {
  const float* x  = (const float*)d_in[0];
  const float* w1 = (const float*)d_in[1];
  const float* b1 = (const float*)d_in[2];
  const float* w2 = (const float*)d_in[3];
  const float* b2 = (const float*)d_in[4];
  float* out = (float*)d_out;
  float* ws  = (float*)d_ws;

  float* Are = ws;
  float* Aim = ws + NPB;
  float* Bre = ws + 2 * NPB;
  float* Bim = ws + 3 * NPB;

  for (int b = 0; b < 4; ++b) {
    k_rfft_w<<<dim3(HH, HD / 64), 256, 0, stream>>>(x, Are, Aim, b);
    k_fft_h<-1><<<dim3(WC, HD / 32), 256, 0, stream>>>(Are, Aim, Bre, Bim);
    k_mlp<<<dim3(HH * WC / 16, NBLK), 256, 0, stream>>>(Bre, Bim, w1, b1, w2, b2, Are, Aim);
    k_fft_h<1><<<dim3(WC, HD / 32), 256, 0, stream>>>(Are, Aim, Bre, Bim);
    k_irfft_w<<<dim3(HH, HD / 64), 256, 0, stream>>>(Bre, Bim, x, out, b);
  }
}

// Round 2
// 3637.558 us; speedup vs baseline: 1.9708x; 1.9708x over previous
//
#include <hip/hip_runtime.h>
#include <hip/hip_bf16.h>
#include <math.h>

// AFNO2D: rfft2(128x128, ortho) -> blockdiag complex MLP (8 x 96, MFMA bf16) -> softshrink
//         -> irfft2 -> +bias.  B=4, H=W=128, C=768.
// ws: 4 * 6,389,760 floats (~97.5 MiB), ping-pong per batch.

#define HD   768
#define NBLK 8
#define BLKC 96
#define HH   128
#define WW   128
#define WC   65

constexpr float SC    = 0.08838834764831845f;      // 1/sqrt(128)
constexpr float TWOPI = 6.28318530717958647692f;
constexpr size_t NPB  = (size_t)HH * WC * HD;      // per-batch plane elems

typedef __attribute__((ext_vector_type(8))) short short8;
typedef __attribute__((ext_vector_type(4))) float f32x4;

static __device__ inline unsigned short f2bf(float f) {
  __hip_bfloat16 h = __float2bfloat16(f);
  return __builtin_bit_cast(unsigned short, h);
}

// ---------------- stage 1: rfft along W (real -> 65 complex), x[b,h,w,c] -> A[h,kw,c]
__global__ __launch_bounds__(256) void k_rfft_w(const float* __restrict__ x,
                                                float* __restrict__ ore,
                                                float* __restrict__ oim, int b) {
  __shared__ float xs[WW][64];
  __shared__ float ct[128], st[128];
  const int h = blockIdx.x, c0 = blockIdx.y * 64, t = threadIdx.x;
  if (t < 128) { float s, c; sincosf((TWOPI / 128.f) * t, &s, &c); ct[t] = c; st[t] = s; }
  const float* xp = x + ((size_t)(b * HH + h)) * WW * HD + c0;
  for (int idx = t; idx < WW * 64; idx += 256) {
    int w = idx >> 6, c = idx & 63;
    xs[w][c] = xp[(size_t)w * HD + c];
  }
  __syncthreads();
  const int c = t & 63, kw0 = t >> 6;
  for (int kw = kw0; kw < WC; kw += 4) {
    float ar = 0.f, ai = 0.f;
    int idx = 0;
    for (int w = 0; w < WW; ++w) {
      float xv = xs[w][c];
      ar = fmaf(xv, ct[idx], ar);
      ai = fmaf(-xv, st[idx], ai);
      idx = (idx + kw) & 127;
    }
    size_t o = ((size_t)h * WC + kw) * HD + c0 + c;
    ore[o] = ar * SC;
    oim[o] = ai * SC;
  }
}

// ---------------- stage 2/4: complex FFT along H. SIGN=-1 forward, +1 inverse. [r,kv,c] -> [ko,kv,c]
template <int SIGN>
__global__ __launch_bounds__(256) void k_fft_h(const float* __restrict__ ire,
                                               const float* __restrict__ iim,
                                               float* __restrict__ ore,
                                               float* __restrict__ oim) {
  __shared__ float zr[128][32], zi[128][32];
  __shared__ float ct[128], st[128];
  const int kv = blockIdx.x, c0 = blockIdx.y * 32, t = threadIdx.x;
  if (t < 128) { float s, c; sincosf((TWOPI / 128.f) * t, &s, &c); ct[t] = c; st[t] = s; }
  for (int idx = t; idx < 128 * 32; idx += 256) {
    int r = idx >> 5, c = idx & 31;
    size_t g = ((size_t)r * WC + kv) * HD + c0 + c;
    zr[r][c] = ire[g];
    zi[r][c] = iim[g];
  }
  __syncthreads();
  const int c = t & 31, g0 = t >> 5;
  for (int ko = g0; ko < 128; ko += 8) {
    float ar = 0.f, ai = 0.f;
    int idx = 0;
    for (int r = 0; r < 128; ++r) {
      float cr = ct[idx], sn = st[idx];
      float vr = zr[r][c], vi = zi[r][c];
      if constexpr (SIGN < 0) {
        ar = fmaf(vr, cr, ar); ar = fmaf(vi, sn, ar);
        ai = fmaf(vi, cr, ai); ai = fmaf(-vr, sn, ai);
      } else {
        ar = fmaf(vr, cr, ar); ar = fmaf(-vi, sn, ar);
        ai = fmaf(vi, cr, ai); ai = fmaf(vr, sn, ai);
      }
      idx = (idx + ko) & 127;
    }
    size_t o = ((size_t)ko * WC + kv) * HD + c0 + c;
    ore[o] = ar * SC;
    oim[o] = ai * SC;
  }
}

// ---------------- stage 3: blockdiag complex MLP + softshrink, MFMA bf16.
// Augmented real GEMM per block n: Waug = [[wa, wb], [-wb, wa]] (192x192).
// WG: 64 positions x 1 channel-block. 4 waves; wave = 16-row strip x 192 cols.
static __device__ inline void stage_w(const float* __restrict__ wg,
                                      unsigned short (*W)[104], int t) {
  for (int idx = t; idx < 96 * 24; idx += 256) {
    int i = idx % 96, o0 = (idx / 96) * 4;
    float4 v = *(const float4*)&wg[i * 96 + o0];   // [i][o] row-major read
    W[o0 + 0][i] = f2bf(v.x);                      // store transposed [o][i]
    W[o0 + 1][i] = f2bf(v.y);
    W[o0 + 2][i] = f2bf(v.z);
    W[o0 + 3][i] = f2bf(v.w);
  }
}

__global__ __launch_bounds__(256) void k_mlp_mfma(
    const float* __restrict__ ire, const float* __restrict__ iim,
    const float* __restrict__ w1, const float* __restrict__ b1,
    const float* __restrict__ w2, const float* __restrict__ b2,
    float* __restrict__ ore, float* __restrict__ oim) {
  __shared__ unsigned short Xs[64][200];   // [row][k] : 0..95 = re, 96..191 = im (pad->200)
  __shared__ unsigned short Wa[96][104];   // transposed [out][in], pad->104 (16B-aligned rows)
  __shared__ unsigned short Wb[96][104];

  const int t = threadIdx.x;
  const int n = blockIdx.y;
  const int p0 = blockIdx.x * 64;
  const int wid = t >> 6, lane = t & 63;
  const int l15 = lane & 15, lg = lane >> 4;

  // ---- stage X tile (bf16)
  for (int idx = t; idx < 64 * 24; idx += 256) {
    int row = idx / 24, seg = idx % 24;
    size_t g = (size_t)(p0 + row) * HD + n * BLKC + seg * 4;
    float4 vr = *(const float4*)&ire[g];
    float4 vi = *(const float4*)&iim[g];
    ushort4 ur = { f2bf(vr.x), f2bf(vr.y), f2bf(vr.z), f2bf(vr.w) };
    ushort4 ui = { f2bf(vi.x), f2bf(vi.y), f2bf(vi.z), f2bf(vi.w) };
    *(ushort4*)&Xs[row][seg * 4] = ur;
    *(ushort4*)&Xs[row][96 + seg * 4] = ui;
  }
  stage_w(w1 + (size_t)n * 9216, Wa, t);
  stage_w(w1 + (size_t)(8 + n) * 9216, Wb, t);

  f32x4 acc[12];
#pragma unroll
  for (int nt = 0; nt < 12; ++nt) {
    int c = nt * 16 + l15;
    float bv = (c < 96) ? b1[n * BLKC + c] : b1[768 + n * BLKC + (c - 96)];
    acc[nt] = { bv, bv, bv, bv };
  }
  __syncthreads();

  // ---- layer 1 GEMM
#pragma unroll
  for (int kk = 0; kk < 6; ++kk) {
    const int k0 = kk * 32 + lg * 8;
    short8 a = *(const short8*)&Xs[wid * 16 + l15][k0];
    const bool hi = (kk >= 3);
    const int k2 = hi ? k0 - 96 : k0;
#pragma unroll
    for (int nt = 0; nt < 12; ++nt) {
      int c = nt * 16 + l15;
      short8 bfr;
      if (nt < 6) {
        if (!hi) bfr = *(const short8*)&Wa[c][k2];
        else {
          int4 nb = *(const int4*)&Wb[c][k2];
          nb.x ^= 0x80008000; nb.y ^= 0x80008000; nb.z ^= 0x80008000; nb.w ^= 0x80008000;
          bfr = __builtin_bit_cast(short8, nb);
        }
      } else {
        bfr = hi ? *(const short8*)&Wa[c - 96][k2] : *(const short8*)&Wb[c - 96][k2];
      }
      acc[nt] = __builtin_amdgcn_mfma_f32_16x16x32_bf16(a, bfr, acc[nt], 0, 0, 0);
    }
  }

  // ---- relu -> O1 back into Xs (wave-private rows; data-dep orders reads before writes)
#pragma unroll
  for (int nt = 0; nt < 12; ++nt) {
    int orow = wid * 16 + lg * 4, oc = nt * 16 + l15;
#pragma unroll
    for (int r = 0; r < 4; ++r)
      Xs[orow + r][oc] = f2bf(fmaxf(acc[nt][r], 0.f));
  }
  __syncthreads();
  stage_w(w2 + (size_t)n * 9216, Wa, t);
  stage_w(w2 + (size_t)(8 + n) * 9216, Wb, t);
#pragma unroll
  for (int nt = 0; nt < 12; ++nt) {
    int c = nt * 16 + l15;
    float bv = (c < 96) ? b2[n * BLKC + c] : b2[768 + n * BLKC + (c - 96)];
    acc[nt] = { bv, bv, bv, bv };
  }
  __syncthreads();

  // ---- layer 2 GEMM
#pragma unroll
  for (int kk = 0; kk < 6; ++kk) {
    const int k0 = kk * 32 + lg * 8;
    short8 a = *(const short8*)&Xs[wid * 16 + l15][k0];
    const bool hi = (kk >= 3);
    const int k2 = hi ? k0 - 96 : k0;
#pragma unroll
    for (int nt = 0; nt < 12; ++nt) {
      int c = nt * 16 + l15;
      short8 bfr;
      if (nt < 6) {
        if (!hi) bfr = *(const short8*)&Wa[c][k2];
        else {
          int4 nb = *(const int4*)&Wb[c][k2];
          nb.x ^= 0x80008000; nb.y ^= 0x80008000; nb.z ^= 0x80008000; nb.w ^= 0x80008000;
          bfr = __builtin_bit_cast(short8, nb);
        }
      } else {
        bfr = hi ? *(const short8*)&Wa[c - 96][k2] : *(const short8*)&Wb[c - 96][k2];
      }
      acc[nt] = __builtin_amdgcn_mfma_f32_16x16x32_bf16(a, bfr, acc[nt], 0, 0, 0);
    }
  }

  // ---- softshrink + store (cols c and c+96 are acc[nt] / acc[nt+6], same lane+reg)
#pragma unroll
  for (int r = 0; r < 4; ++r) {
    int p = p0 + wid * 16 + lg * 4 + r;
    int ku = p / WC, kv = p - ku * WC;
    float kus = (ku >= 64) ? (float)(ku - 128) : (float)ku;
    float k2v = kus * kus + (float)(kv * kv);
    float thr = fmaxf(0.01f * expf(-0.00125f * k2v), 0.0005f);
#pragma unroll
    for (int nt = 0; nt < 6; ++nt) {
      float mr = acc[nt][r], mi = acc[nt + 6][r];
      float mag = sqrtf(mr * mr + mi * mi + 1e-8f);
      float sf = fmaxf(mag - thr, 0.f) / mag;
      size_t g = (size_t)p * HD + n * BLKC + nt * 16 + l15;
      ore[g] = mr * sf;
      oim[g] = mi * sf;
    }
  }
}

// ---------------- stage 5: irfft along W (numpy c2r semantics: imag of bins 0,64 ignored) + bias
__global__ __launch_bounds__(256) void k_irfft_w(const float* __restrict__ ire,
                                                 const float* __restrict__ iim,
                                                 const float* __restrict__ x,
                                                 float* __restrict__ out, int b) {
  __shared__ float zr[WC][64], zi[WC][64];
  __shared__ float ct[128], st[128];
  const int h = blockIdx.x, c0 = blockIdx.y * 64, t = threadIdx.x;
  if (t < 128) { float s, c; sincosf((TWOPI / 128.f) * t, &s, &c); ct[t] = c; st[t] = s; }
  for (int idx = t; idx < WC * 64; idx += 256) {
    int kv = idx >> 6, c = idx & 63;
    size_t g = ((size_t)h * WC + kv) * HD + c0 + c;
    zr[kv][c] = ire[g];
    zi[kv][c] = iim[g];
  }
  __syncthreads();
  const int c = t & 63, w0 = t >> 6;
  for (int w = w0; w < WW; w += 4) {
    float acc = zr[0][c] + ((w & 1) ? -zr[64][c] : zr[64][c]);
    int idx = w;
    for (int k = 1; k < 64; ++k) {
      acc += 2.f * fmaf(zr[k][c], ct[idx], -zi[k][c] * st[idx]);
      idx = (idx + w) & 127;
    }
    size_t go = (((size_t)(b * HH + h)) * WW + w) * HD + c0 + c;
    out[go] = fmaf(acc, SC, x[go]);
  }
}

extern "C" void kernel_launch(void* const* d_in, const int* in_sizes, int n_in,
                              void* d_out, int out_size, void* d_ws, size_t ws_size,
                              hipStream_t stream) {
  const float* x  = (const float*)d_in[0];
  const float* w1 = (const float*)d_in[1];
  const float* b1 = (const float*)d_in[2];
  const float* w2 = (const float*)d_in[3];
  const float* b2 = (const float*)d_in[4];
  float* out = (float*)d_out;
  float* ws  = (float*)d_ws;

  float* Are = ws;
  float* Aim = ws + NPB;
  float* Bre = ws + 2 * NPB;
  float* Bim = ws + 3 * NPB;

  for (int b = 0; b < 4; ++b) {
    k_rfft_w<<<dim3(HH, HD / 64), 256, 0, stream>>>(x, Are, Aim, b);
    k_fft_h<-1><<<dim3(WC, HD / 32), 256, 0, stream>>>(Are, Aim, Bre, Bim);
    k_mlp_mfma<<<dim3(HH * WC / 64, NBLK), 256, 0, stream>>>(Bre, Bim, w1, b1, w2, b2, Are, Aim);
    k_fft_h<1><<<dim3(WC, HD / 32), 256, 0, stream>>>(Are, Aim, Bre, Bim);
    k_irfft_w<<<dim3(HH, HD / 64), 256, 0, stream>>>(Bre, Bim, x, out, b);
  }
}

// Round 3
// 823.999 us; speedup vs baseline: 8.7003x; 4.4145x over previous
//
#include <hip/hip_runtime.h>
#include <hip/hip_bf16.h>
#include <math.h>

// AFNO2D: rfft2(128x128, ortho) -> blockdiag complex MLP (8 x 96, MFMA bf16) -> softshrink
//         -> irfft2 -> +bias.  B=4, H=W=128, C=768.
// All FFT stages: in-LDS radix-4 (4,4,4,2) fp32 FFT, 32 lines/WG.
// ws: 4 * NPB floats (~102 MB) ping-pong planes. Packed bf16 weights live in the
// tail 1MB of d_out (overwritten by batch-3 output AFTER last use).

#define HD   768
#define NBLK 8
#define BLKC 96
#define HH   128
#define WW   128
#define WC   65
#define LSTR 130   // LDS line stride (dwords) for 128-point FFT lines
#define WSTR 120   // packed weight row stride (ushorts) = 240B, 16B-aligned

constexpr float SC    = 0.08838834764831845f;      // 1/sqrt(128)
constexpr float TWOPI = 6.28318530717958647692f;
constexpr size_t NPB  = (size_t)HH * WC * HD;      // per-batch plane elems
constexpr int WPK_MAT  = 96 * WSTR;                // ushorts per packed matrix (11520)
constexpr int WPK_U16  = 2 * NBLK * 2 * WPK_MAT;   // total packed ushorts (368640)
constexpr int WPK_F32  = WPK_U16 / 2;              // floats spanned by weights (184320)
constexpr int TAIL_F32 = 262144;                   // 1MB tail of d_out reserved

typedef __attribute__((ext_vector_type(8))) short short8;
typedef __attribute__((ext_vector_type(4))) float f32x4;

static __device__ inline unsigned short f2bf(float f) {
  __hip_bfloat16 h = __float2bfloat16(f);
  return __builtin_bit_cast(unsigned short, h);
}

// digit-reversed output index for DIF passes radix 4,4,4,2
static __device__ inline int revidx(int p) {
  return ((p >> 5) & 3) | (((p >> 3) & 3) << 2) | (((p >> 1) & 3) << 4) | ((p & 1) << 6);
}

// one radix-4 DIF pass over 32 lines in LDS. S = segment len, q = S/4, step = 128/S.
template <int SIGN, int S, int Q, int STEP>
static __device__ inline void fft_pass4(float* Zr, float* Zi,
                                        const float* ct, const float* st,
                                        int l, int tsub) {
  float* zr = Zr + l * LSTR;
  float* zi = Zi + l * LSTR;
#pragma unroll
  for (int i = 0; i < 4; ++i) {
    int gg = tsub + 8 * i;
    int seg = gg / Q, j = gg - seg * Q;
    int b0 = seg * S + j;
    float x0r = zr[b0],         x0i = zi[b0];
    float x1r = zr[b0 + Q],     x1i = zi[b0 + Q];
    float x2r = zr[b0 + 2 * Q], x2i = zi[b0 + 2 * Q];
    float x3r = zr[b0 + 3 * Q], x3i = zi[b0 + 3 * Q];
    float apr = x0r + x2r, api = x0i + x2i;
    float amr = x0r - x2r, ami = x0i - x2i;
    float bpr = x1r + x3r, bpi = x1i + x3i;
    float bmr = x1r - x3r, bmi = x1i - x3i;
    float u0r = apr + bpr, u0i = api + bpi;
    float u2r = apr - bpr, u2i = api - bpi;
    float u1r, u1i, u3r, u3i;
    if constexpr (SIGN < 0) {          // forward: u1 = am - i*bm ; u3 = am + i*bm
      u1r = amr + bmi; u1i = ami - bmr;
      u3r = amr - bmi; u3i = ami + bmr;
    } else {                           // inverse: u1 = am + i*bm ; u3 = am - i*bm
      u1r = amr - bmi; u1i = ami + bmr;
      u3r = amr + bmi; u3i = ami - bmr;
    }
    int i1 = (j * STEP) & 127, i2 = (2 * j * STEP) & 127, i3 = (3 * j * STEP) & 127;
    float c1 = ct[i1], s1 = st[i1], c2 = ct[i2], s2 = st[i2], c3 = ct[i3], s3 = st[i3];
    float v1r, v1i, v2r, v2i, v3r, v3i;
    if constexpr (SIGN < 0) {          // * (c - i s)
      v1r = u1r * c1 + u1i * s1; v1i = u1i * c1 - u1r * s1;
      v2r = u2r * c2 + u2i * s2; v2i = u2i * c2 - u2r * s2;
      v3r = u3r * c3 + u3i * s3; v3i = u3i * c3 - u3r * s3;
    } else {                           // * (c + i s)
      v1r = u1r * c1 - u1i * s1; v1i = u1i * c1 + u1r * s1;
      v2r = u2r * c2 - u2i * s2; v2i = u2i * c2 + u2r * s2;
      v3r = u3r * c3 - u3i * s3; v3i = u3i * c3 + u3r * s3;
    }
    zr[b0] = u0r;         zi[b0] = u0i;
    zr[b0 + Q] = v1r;     zi[b0 + Q] = v1i;
    zr[b0 + 2 * Q] = v2r; zi[b0 + 2 * Q] = v2i;
    zr[b0 + 3 * Q] = v3r; zi[b0 + 3 * Q] = v3i;
  }
}

template <int SIGN>
static __device__ inline void fft128(float* Zr, float* Zi,
                                     const float* ct, const float* st, int t) {
  const int l = t >> 3, tsub = t & 7;
  __syncthreads();
  fft_pass4<SIGN, 128, 32, 1>(Zr, Zi, ct, st, l, tsub);
  __syncthreads();
  fft_pass4<SIGN, 32, 8, 4>(Zr, Zi, ct, st, l, tsub);
  __syncthreads();
  fft_pass4<SIGN, 8, 2, 16>(Zr, Zi, ct, st, l, tsub);
  __syncthreads();
  // final radix-2 (twiddle = 1)
  float* zr = Zr + l * LSTR;
  float* zi = Zi + l * LSTR;
#pragma unroll
  for (int i = 0; i < 8; ++i) {
    int b0 = 2 * (tsub + 8 * i);
    float ar = zr[b0], ai = zi[b0], br = zr[b0 + 1], bi = zi[b0 + 1];
    zr[b0] = ar + br;     zi[b0] = ai + bi;
    zr[b0 + 1] = ar - br; zi[b0 + 1] = ai - bi;
  }
  __syncthreads();
}

static __device__ inline void fill_tab(float* ct, float* st, int t) {
  if (t < 128) {
    float s, c;
    sincosf((TWOPI / 128.f) * t, &s, &c);
    ct[t] = c; st[t] = s;
  }
}

// ---------------- stage 1: rfft along W (real -> keep bins 0..64)
__global__ __launch_bounds__(256) void k_fft_w(const float* __restrict__ x,
                                               float* __restrict__ ore,
                                               float* __restrict__ oim, int b) {
  __shared__ float Zr[32 * LSTR], Zi[32 * LSTR];
  __shared__ float ct[128], st[128];
  const int h = blockIdx.x, c0 = blockIdx.y * 32, t = threadIdx.x;
  fill_tab(ct, st, t);
  const float* xp = x + ((size_t)(b * HH + h)) * WW * HD + c0;
  for (int idx = t; idx < 32 * 128; idx += 256) {
    int w = idx >> 5, l = idx & 31;
    Zr[l * LSTR + w] = xp[(size_t)w * HD + l];
    Zi[l * LSTR + w] = 0.f;
  }
  fft128<-1>(Zr, Zi, ct, st, t);
  for (int idx = t; idx < 32 * 128; idx += 256) {
    int p = idx >> 5, l = idx & 31;
    int k = revidx(p);
    if (k < WC) {
      size_t o = ((size_t)h * WC + k) * HD + c0 + l;
      ore[o] = Zr[l * LSTR + p] * SC;
      oim[o] = Zi[l * LSTR + p] * SC;
    }
  }
}

// ---------------- stage 2/4: complex FFT along H (SIGN=-1 fwd, +1 inv)
template <int SIGN>
__global__ __launch_bounds__(256) void k_fft_h(const float* __restrict__ ire,
                                               const float* __restrict__ iim,
                                               float* __restrict__ ore,
                                               float* __restrict__ oim) {
  __shared__ float Zr[32 * LSTR], Zi[32 * LSTR];
  __shared__ float ct[128], st[128];
  const int kv = blockIdx.x, c0 = blockIdx.y * 32, t = threadIdx.x;
  fill_tab(ct, st, t);
  for (int idx = t; idx < 32 * 128; idx += 256) {
    int r = idx >> 5, l = idx & 31;
    size_t g = ((size_t)r * WC + kv) * HD + c0 + l;
    Zr[l * LSTR + r] = ire[g];
    Zi[l * LSTR + r] = iim[g];
  }
  fft128<SIGN>(Zr, Zi, ct, st, t);
  for (int idx = t; idx < 32 * 128; idx += 256) {
    int p = idx >> 5, l = idx & 31;
    int k = revidx(p);
    size_t o = ((size_t)k * WC + kv) * HD + c0 + l;
    ore[o] = Zr[l * LSTR + p] * SC;
    oim[o] = Zi[l * LSTR + p] * SC;
  }
}

// ---------------- stage 5: irfft along W (numpy c2r: imag of bins 0,64 ignored) + bias
__global__ __launch_bounds__(256) void k_ifft_w(const float* __restrict__ ire,
                                                const float* __restrict__ iim,
                                                const float* __restrict__ x,
                                                float* __restrict__ out, int b) {
  __shared__ float Zr[32 * LSTR], Zi[32 * LSTR];
  __shared__ float ct[128], st[128];
  const int ku = blockIdx.x, c0 = blockIdx.y * 32, t = threadIdx.x;
  fill_tab(ct, st, t);
  for (int idx = t; idx < 32 * WC; idx += 256) {
    int k = idx >> 5, l = idx & 31;
    size_t g = ((size_t)ku * WC + k) * HD + c0 + l;
    Zr[l * LSTR + k] = ire[g];
    Zi[l * LSTR + k] = (k == 0 || k == 64) ? 0.f : iim[g];
  }
  __syncthreads();
  // Hermitian mirror: bins 65..127 from 1..63
  for (int idx = t; idx < 32 * 63; idx += 256) {
    int k = 65 + (idx >> 5), l = idx & 31;
    Zr[l * LSTR + k] = Zr[l * LSTR + (128 - k)];
    Zi[l * LSTR + k] = -Zi[l * LSTR + (128 - k)];
  }
  fft128<1>(Zr, Zi, ct, st, t);
  const size_t rowbase = ((size_t)(b * HH + ku)) * WW * HD + c0;
  for (int idx = t; idx < 32 * 128; idx += 256) {
    int p = idx >> 5, l = idx & 31;
    int w = revidx(p);
    size_t go = rowbase + (size_t)w * HD + l;
    out[go] = fmaf(Zr[l * LSTR + p], SC, x[go]);
  }
}

// ---------------- weight pre-pack: transposed bf16 wa/wb (stride 120) + augmented biases
__global__ __launch_bounds__(256) void k_prep(const float* __restrict__ w1,
                                              const float* __restrict__ b1,
                                              const float* __restrict__ w2,
                                              const float* __restrict__ b2,
                                              unsigned short* __restrict__ wpk,
                                              float* __restrict__ bpk) {
  const int layer = blockIdx.x >> 3, n = blockIdx.x & 7;
  const float* w = layer ? w2 : w1;
  const float* bsrc = layer ? b2 : b1;
  for (int m = 0; m < 2; ++m) {
    const float* src = w + (size_t)(m * NBLK + n) * 9216;    // [i][o] 96x96
    unsigned short* dst = wpk + ((size_t)blockIdx.x * 2 + m) * WPK_MAT;
    for (int idx = threadIdx.x; idx < 9216; idx += 256) {
      int o = idx / 96, i = idx - o * 96;
      dst[o * WSTR + i] = f2bf(src[i * 96 + o]);             // store [o][i]
    }
  }
  for (int c = threadIdx.x; c < 192; c += 256)
    bpk[blockIdx.x * 192 + c] = (c < 96) ? bsrc[n * 96 + c] : bsrc[(NBLK + n) * 96 + (c - 96)];
}

// ---------------- stage 3: blockdiag complex MLP + softshrink, MFMA bf16, packed weights
__global__ __launch_bounds__(256) void k_mlp2(
    const float* __restrict__ ire, const float* __restrict__ iim,
    const unsigned short* __restrict__ wpk, const float* __restrict__ bpk,
    float* __restrict__ ore, float* __restrict__ oim) {
  __shared__ unsigned short Xs[64][200];   // [row][k]: 0..95 re, 96..191 im
  __shared__ unsigned short Wa[96][WSTR];
  __shared__ unsigned short Wb[96][WSTR];

  const int t = threadIdx.x;
  const int n = blockIdx.y;
  const int p0 = blockIdx.x * 64;
  const int wid = t >> 6, lane = t & 63;
  const int l15 = lane & 15, lg = lane >> 4;

  // stage X tile (fp32 -> bf16)
  for (int idx = t; idx < 64 * 24; idx += 256) {
    int row = idx / 24, seg = idx % 24;
    size_t g = (size_t)(p0 + row) * HD + n * BLKC + seg * 4;
    float4 vr = *(const float4*)&ire[g];
    float4 vi = *(const float4*)&iim[g];
    ushort4 ur = { f2bf(vr.x), f2bf(vr.y), f2bf(vr.z), f2bf(vr.w) };
    ushort4 ui = { f2bf(vi.x), f2bf(vi.y), f2bf(vi.z), f2bf(vi.w) };
    *(ushort4*)&Xs[row][seg * 4] = ur;
    *(ushort4*)&Xs[row][96 + seg * 4] = ui;
  }
  // stage layer-1 weights (pure int4 copy)
  {
    const int4* sa = (const int4*)(wpk + ((size_t)(0 * NBLK + n) * 2 + 0) * WPK_MAT);
    const int4* sb = (const int4*)(wpk + ((size_t)(0 * NBLK + n) * 2 + 1) * WPK_MAT);
    for (int idx = t; idx < WPK_MAT / 8; idx += 256) {
      ((int4*)Wa)[idx] = sa[idx];
      ((int4*)Wb)[idx] = sb[idx];
    }
  }
  f32x4 acc[12];
#pragma unroll
  for (int nt = 0; nt < 12; ++nt) {
    float bv = bpk[n * 192 + nt * 16 + l15];
    acc[nt] = { bv, bv, bv, bv };
  }
  __syncthreads();

  // layer 1 GEMM
#pragma unroll
  for (int kk = 0; kk < 6; ++kk) {
    const int k0 = kk * 32 + lg * 8;
    short8 a = *(const short8*)&Xs[wid * 16 + l15][k0];
    const bool hi = (kk >= 3);
    const int k2 = hi ? k0 - 96 : k0;
#pragma unroll
    for (int nt = 0; nt < 12; ++nt) {
      int c = nt * 16 + l15;
      short8 bfr;
      if (nt < 6) {
        if (!hi) bfr = *(const short8*)&Wa[c][k2];
        else {
          int4 nb = *(const int4*)&Wb[c][k2];
          nb.x ^= 0x80008000; nb.y ^= 0x80008000; nb.z ^= 0x80008000; nb.w ^= 0x80008000;
          bfr = __builtin_bit_cast(short8, nb);
        }
      } else {
        bfr = hi ? *(const short8*)&Wa[c - 96][k2] : *(const short8*)&Wb[c - 96][k2];
      }
      acc[nt] = __builtin_amdgcn_mfma_f32_16x16x32_bf16(a, bfr, acc[nt], 0, 0, 0);
    }
  }

  // relu -> O1 back into Xs (wave-private rows)
#pragma unroll
  for (int nt = 0; nt < 12; ++nt) {
    int orow = wid * 16 + lg * 4, oc = nt * 16 + l15;
#pragma unroll
    for (int r = 0; r < 4; ++r)
      Xs[orow + r][oc] = f2bf(fmaxf(acc[nt][r], 0.f));
  }
  __syncthreads();
  // stage layer-2 weights
  {
    const int4* sa = (const int4*)(wpk + ((size_t)(1 * NBLK + n) * 2 + 0) * WPK_MAT);
    const int4* sb = (const int4*)(wpk + ((size_t)(1 * NBLK + n) * 2 + 1) * WPK_MAT);
    for (int idx = t; idx < WPK_MAT / 8; idx += 256) {
      ((int4*)Wa)[idx] = sa[idx];
      ((int4*)Wb)[idx] = sb[idx];
    }
  }
#pragma unroll
  for (int nt = 0; nt < 12; ++nt) {
    float bv = bpk[(NBLK + n) * 192 + nt * 16 + l15];
    acc[nt] = { bv, bv, bv, bv };
  }
  __syncthreads();

  // layer 2 GEMM
#pragma unroll
  for (int kk = 0; kk < 6; ++kk) {
    const int k0 = kk * 32 + lg * 8;
    short8 a = *(const short8*)&Xs[wid * 16 + l15][k0];
    const bool hi = (kk >= 3);
    const int k2 = hi ? k0 - 96 : k0;
#pragma unroll
    for (int nt = 0; nt < 12; ++nt) {
      int c = nt * 16 + l15;
      short8 bfr;
      if (nt < 6) {
        if (!hi) bfr = *(const short8*)&Wa[c][k2];
        else {
          int4 nb = *(const int4*)&Wb[c][k2];
          nb.x ^= 0x80008000; nb.y ^= 0x80008000; nb.z ^= 0x80008000; nb.w ^= 0x80008000;
          bfr = __builtin_bit_cast(short8, nb);
        }
      } else {
        bfr = hi ? *(const short8*)&Wa[c - 96][k2] : *(const short8*)&Wb[c - 96][k2];
      }
      acc[nt] = __builtin_amdgcn_mfma_f32_16x16x32_bf16(a, bfr, acc[nt], 0, 0, 0);
    }
  }

  // softshrink + store
#pragma unroll
  for (int r = 0; r < 4; ++r) {
    int p = p0 + wid * 16 + lg * 4 + r;
    int ku = p / WC, kv = p - ku * WC;
    float kus = (ku >= 64) ? (float)(ku - 128) : (float)ku;
    float k2v = kus * kus + (float)(kv * kv);
    float thr = fmaxf(0.01f * expf(-0.00125f * k2v), 0.0005f);
#pragma unroll
    for (int nt = 0; nt < 6; ++nt) {
      float mr = acc[nt][r], mi = acc[nt + 6][r];
      float mag = sqrtf(mr * mr + mi * mi + 1e-8f);
      float sf = fmaxf(mag - thr, 0.f) / mag;
      size_t g = (size_t)p * HD + n * BLKC + nt * 16 + l15;
      ore[g] = mr * sf;
      oim[g] = mi * sf;
    }
  }
}

extern "C" void kernel_launch(void* const* d_in, const int* in_sizes, int n_in,
                              void* d_out, int out_size, void* d_ws, size_t ws_size,
                              hipStream_t stream) {
  const float* x  = (const float*)d_in[0];
  const float* w1 = (const float*)d_in[1];
  const float* b1 = (const float*)d_in[2];
  const float* w2 = (const float*)d_in[3];
  const float* b2 = (const float*)d_in[4];
  float* out = (float*)d_out;
  float* ws  = (float*)d_ws;

  float* Are = ws;
  float* Aim = ws + NPB;
  float* Bre = ws + 2 * NPB;
  float* Bim = ws + 3 * NPB;

  // packed weights live in the tail of d_out; batch-3 ifft overwrites them
  // only after the last weight read (same-stream ordering).
  float* tail = out + ((size_t)out_size - TAIL_F32);
  unsigned short* wpk = (unsigned short*)tail;
  float* bpk = tail + WPK_F32;

  k_prep<<<16, 256, 0, stream>>>(w1, b1, w2, b2, wpk, bpk);

  for (int b = 0; b < 4; ++b) {
    k_fft_w<<<dim3(HH, HD / 32), 256, 0, stream>>>(x, Are, Aim, b);
    k_fft_h<-1><<<dim3(WC, HD / 32), 256, 0, stream>>>(Are, Aim, Bre, Bim);
    k_mlp2<<<dim3(HH * WC / 64, NBLK), 256, 0, stream>>>(Bre, Bim, wpk, bpk, Are, Aim);
    k_fft_h<1><<<dim3(WC, HD / 32), 256, 0, stream>>>(Are, Aim, Bre, Bim);
    k_ifft_w<<<dim3(HH, HD / 32), 256, 0, stream>>>(Bre, Bim, x, out, b);
  }
}

// Round 4
// 630.079 us; speedup vs baseline: 11.3780x; 1.3078x over previous
//
#include <hip/hip_runtime.h>
#include <hip/hip_bf16.h>
#include <math.h>

// AFNO2D: rfft2(128x128, ortho) -> blockdiag complex MLP (8 x 96, MFMA bf16) -> softshrink
//         -> irfft2 -> +bias.  B=4, H=W=128, C=768.
// Spectral plane stored ONCE in ws as packed bf16 (re|im in one uint per point),
// layout A[b][pos][c], pos = h*65+kw. fft_h fwd / MLP / fft_h inv run IN-PLACE
// (each WG reads+writes an exclusive slice). 6 launches total, all batches per grid.

#define HD   768
#define NBLK 8
#define BLKC 96
#define HH   128
#define WW   128
#define WC   65
#define NPOS (HH * WC)            // 8320 positions per batch
#define LSTR 130                  // LDS line stride (dwords)
#define WSTR 120                  // packed weight row stride (ushorts)

constexpr float SC    = 0.08838834764831845f;      // 1/sqrt(128)
constexpr float TWOPI = 6.28318530717958647692f;
constexpr int WPK_MAT  = 96 * WSTR;
constexpr int WPK_F32  = 2 * NBLK * 2 * WPK_MAT / 2;
constexpr int TAIL_F32 = 262144;                   // 1MB tail of d_out for packed weights

typedef __attribute__((ext_vector_type(8))) short short8;
typedef __attribute__((ext_vector_type(4))) float f32x4;

static __device__ inline unsigned short f2bf(float f) {
  __hip_bfloat16 h = __float2bfloat16(f);
  return __builtin_bit_cast(unsigned short, h);
}
static __device__ inline unsigned int pack2(float re, float im) {
  return (unsigned int)f2bf(re) | ((unsigned int)f2bf(im) << 16);
}
static __device__ inline float lo2f(unsigned int u) {
  return __builtin_bit_cast(float, u << 16);
}
static __device__ inline float hi2f(unsigned int u) {
  return __builtin_bit_cast(float, u & 0xffff0000u);
}

// digit-reversed output index for DIF passes radix 4,4,4,2
static __device__ inline int revidx(int p) {
  return ((p >> 5) & 3) | (((p >> 3) & 3) << 2) | (((p >> 1) & 3) << 4) | ((p & 1) << 6);
}

template <int SIGN, int S, int Q, int STEP>
static __device__ inline void fft_pass4(float* Zr, float* Zi,
                                        const float* ct, const float* st,
                                        int l, int tsub) {
  float* zr = Zr + l * LSTR;
  float* zi = Zi + l * LSTR;
#pragma unroll
  for (int i = 0; i < 4; ++i) {
    int gg = tsub + 8 * i;
    int seg = gg / Q, j = gg - seg * Q;
    int b0 = seg * S + j;
    float x0r = zr[b0],         x0i = zi[b0];
    float x1r = zr[b0 + Q],     x1i = zi[b0 + Q];
    float x2r = zr[b0 + 2 * Q], x2i = zi[b0 + 2 * Q];
    float x3r = zr[b0 + 3 * Q], x3i = zi[b0 + 3 * Q];
    float apr = x0r + x2r, api = x0i + x2i;
    float amr = x0r - x2r, ami = x0i - x2i;
    float bpr = x1r + x3r, bpi = x1i + x3i;
    float bmr = x1r - x3r, bmi = x1i - x3i;
    float u0r = apr + bpr, u0i = api + bpi;
    float u2r = apr - bpr, u2i = api - bpi;
    float u1r, u1i, u3r, u3i;
    if constexpr (SIGN < 0) {
      u1r = amr + bmi; u1i = ami - bmr;
      u3r = amr - bmi; u3i = ami + bmr;
    } else {
      u1r = amr - bmi; u1i = ami + bmr;
      u3r = amr + bmi; u3i = ami - bmr;
    }
    int i1 = (j * STEP) & 127, i2 = (2 * j * STEP) & 127, i3 = (3 * j * STEP) & 127;
    float c1 = ct[i1], s1 = st[i1], c2 = ct[i2], s2 = st[i2], c3 = ct[i3], s3 = st[i3];
    float v1r, v1i, v2r, v2i, v3r, v3i;
    if constexpr (SIGN < 0) {
      v1r = u1r * c1 + u1i * s1; v1i = u1i * c1 - u1r * s1;
      v2r = u2r * c2 + u2i * s2; v2i = u2i * c2 - u2r * s2;
      v3r = u3r * c3 + u3i * s3; v3i = u3i * c3 - u3r * s3;
    } else {
      v1r = u1r * c1 - u1i * s1; v1i = u1i * c1 + u1r * s1;
      v2r = u2r * c2 - u2i * s2; v2i = u2i * c2 + u2r * s2;
      v3r = u3r * c3 - u3i * s3; v3i = u3i * c3 + u3r * s3;
    }
    zr[b0] = u0r;         zi[b0] = u0i;
    zr[b0 + Q] = v1r;     zi[b0 + Q] = v1i;
    zr[b0 + 2 * Q] = v2r; zi[b0 + 2 * Q] = v2i;
    zr[b0 + 3 * Q] = v3r; zi[b0 + 3 * Q] = v3i;
  }
}

template <int SIGN>
static __device__ inline void fft128(float* Zr, float* Zi,
                                     const float* ct, const float* st, int t) {
  const int l = t >> 3, tsub = t & 7;
  __syncthreads();
  fft_pass4<SIGN, 128, 32, 1>(Zr, Zi, ct, st, l, tsub);
  __syncthreads();
  fft_pass4<SIGN, 32, 8, 4>(Zr, Zi, ct, st, l, tsub);
  __syncthreads();
  fft_pass4<SIGN, 8, 2, 16>(Zr, Zi, ct, st, l, tsub);
  __syncthreads();
  float* zr = Zr + l * LSTR;
  float* zi = Zi + l * LSTR;
#pragma unroll
  for (int i = 0; i < 8; ++i) {
    int b0 = 2 * (tsub + 8 * i);
    float ar = zr[b0], ai = zi[b0], br = zr[b0 + 1], bi = zi[b0 + 1];
    zr[b0] = ar + br;     zi[b0] = ai + bi;
    zr[b0 + 1] = ar - br; zi[b0 + 1] = ai - bi;
  }
  __syncthreads();
}

static __device__ inline void fill_tab(float* ct, float* st, int t) {
  if (t < 128) {
    float s, c;
    sincosf((TWOPI / 128.f) * t, &s, &c);
    ct[t] = c; st[t] = s;
  }
}

// ---------------- stage 1: rfft along W, x -> packed A (bins 0..64)
__global__ __launch_bounds__(256) void k_fft_w(const float* __restrict__ x,
                                               unsigned int* __restrict__ A) {
  __shared__ float Zr[32 * LSTR], Zi[32 * LSTR];
  __shared__ float ct[128], st[128];
  const int h = blockIdx.x, c0 = blockIdx.y * 32, b = blockIdx.z, t = threadIdx.x;
  fill_tab(ct, st, t);
  const float* xp = x + ((size_t)(b * HH + h)) * WW * HD + c0;
  for (int idx = t; idx < 32 * 128; idx += 256) {
    int w = idx >> 5, l = idx & 31;
    Zr[l * LSTR + w] = xp[(size_t)w * HD + l];
    Zi[l * LSTR + w] = 0.f;
  }
  fft128<-1>(Zr, Zi, ct, st, t);
  for (int idx = t; idx < 32 * 128; idx += 256) {
    int p = idx >> 5, l = idx & 31;
    int k = revidx(p);
    if (k < WC) {
      size_t o = ((size_t)b * NPOS + h * WC + k) * HD + c0 + l;
      A[o] = pack2(Zr[l * LSTR + p] * SC, Zi[l * LSTR + p] * SC);
    }
  }
}

// ---------------- stage 2/4: complex FFT along H, IN-PLACE on packed A
template <int SIGN>
__global__ __launch_bounds__(256) void k_fft_h(unsigned int* __restrict__ A) {
  __shared__ float Zr[32 * LSTR], Zi[32 * LSTR];
  __shared__ float ct[128], st[128];
  const int kv = blockIdx.x, c0 = blockIdx.y * 32, b = blockIdx.z, t = threadIdx.x;
  fill_tab(ct, st, t);
  for (int idx = t; idx < 32 * 128; idx += 256) {
    int r = idx >> 5, l = idx & 31;
    unsigned int u = A[((size_t)b * NPOS + r * WC + kv) * HD + c0 + l];
    Zr[l * LSTR + r] = lo2f(u);
    Zi[l * LSTR + r] = hi2f(u);
  }
  fft128<SIGN>(Zr, Zi, ct, st, t);
  for (int idx = t; idx < 32 * 128; idx += 256) {
    int p = idx >> 5, l = idx & 31;
    int k = revidx(p);
    size_t o = ((size_t)b * NPOS + k * WC + kv) * HD + c0 + l;
    A[o] = pack2(Zr[l * LSTR + p] * SC, Zi[l * LSTR + p] * SC);
  }
}

// ---------------- stage 5: irfft along W (numpy c2r: imag of bins 0,64 ignored) + bias
__global__ __launch_bounds__(256) void k_ifft_w(const unsigned int* __restrict__ A,
                                                const float* __restrict__ x,
                                                float* __restrict__ out) {
  __shared__ float Zr[32 * LSTR], Zi[32 * LSTR];
  __shared__ float ct[128], st[128];
  const int ku = blockIdx.x, c0 = blockIdx.y * 32, b = blockIdx.z, t = threadIdx.x;
  fill_tab(ct, st, t);
  for (int idx = t; idx < 32 * WC; idx += 256) {
    int k = idx >> 5, l = idx & 31;
    unsigned int u = A[((size_t)b * NPOS + ku * WC + k) * HD + c0 + l];
    Zr[l * LSTR + k] = lo2f(u);
    Zi[l * LSTR + k] = (k == 0 || k == 64) ? 0.f : hi2f(u);
  }
  __syncthreads();
  for (int idx = t; idx < 32 * 63; idx += 256) {
    int k = 65 + (idx >> 5), l = idx & 31;
    Zr[l * LSTR + k] = Zr[l * LSTR + (128 - k)];
    Zi[l * LSTR + k] = -Zi[l * LSTR + (128 - k)];
  }
  fft128<1>(Zr, Zi, ct, st, t);
  const size_t rowbase = ((size_t)(b * HH + ku)) * WW * HD + c0;
  for (int idx = t; idx < 32 * 128; idx += 256) {
    int p = idx >> 5, l = idx & 31;
    int w = revidx(p);
    size_t go = rowbase + (size_t)w * HD + l;
    out[go] = fmaf(Zr[l * LSTR + p], SC, x[go]);
  }
}

// ---------------- weight pre-pack: transposed bf16 wa/wb + augmented biases
__global__ __launch_bounds__(256) void k_prep(const float* __restrict__ w1,
                                              const float* __restrict__ b1,
                                              const float* __restrict__ w2,
                                              const float* __restrict__ b2,
                                              unsigned short* __restrict__ wpk,
                                              float* __restrict__ bpk) {
  const int layer = blockIdx.x >> 3, n = blockIdx.x & 7;
  const float* w = layer ? w2 : w1;
  const float* bsrc = layer ? b2 : b1;
  for (int m = 0; m < 2; ++m) {
    const float* src = w + (size_t)(m * NBLK + n) * 9216;
    unsigned short* dst = wpk + ((size_t)blockIdx.x * 2 + m) * WPK_MAT;
    for (int idx = threadIdx.x; idx < 9216; idx += 256) {
      int o = idx / 96, i = idx - o * 96;
      dst[o * WSTR + i] = f2bf(src[i * 96 + o]);
    }
  }
  for (int c = threadIdx.x; c < 192; c += 256)
    bpk[blockIdx.x * 192 + c] = (c < 96) ? bsrc[n * 96 + c] : bsrc[(NBLK + n) * 96 + (c - 96)];
}

// ---------------- stage 3: blockdiag complex MLP + softshrink, MFMA bf16, IN-PLACE
__global__ __launch_bounds__(256) void k_mlp2(
    unsigned int* __restrict__ A,
    const unsigned short* __restrict__ wpk, const float* __restrict__ bpk) {
  __shared__ unsigned short Xs[64][200];
  __shared__ unsigned short Wa[96][WSTR];
  __shared__ unsigned short Wb[96][WSTR];

  const int t = threadIdx.x;
  const int n = blockIdx.y;
  const int b = blockIdx.z;
  const int p0 = blockIdx.x * 64;
  const int wid = t >> 6, lane = t & 63;
  const int l15 = lane & 15, lg = lane >> 4;

  // stage X tile: packed uint4 = 4 complex points -> bit-slice into re/im halves
  for (int idx = t; idx < 64 * 24; idx += 256) {
    int row = idx / 24, seg = idx % 24;
    uint4 v = *(const uint4*)&A[((size_t)b * NPOS + p0 + row) * HD + n * BLKC + seg * 4];
    ushort4 ur = { (unsigned short)(v.x & 0xffff), (unsigned short)(v.y & 0xffff),
                   (unsigned short)(v.z & 0xffff), (unsigned short)(v.w & 0xffff) };
    ushort4 ui = { (unsigned short)(v.x >> 16), (unsigned short)(v.y >> 16),
                   (unsigned short)(v.z >> 16), (unsigned short)(v.w >> 16) };
    *(ushort4*)&Xs[row][seg * 4] = ur;
    *(ushort4*)&Xs[row][96 + seg * 4] = ui;
  }
  {
    const int4* sa = (const int4*)(wpk + ((size_t)(0 * NBLK + n) * 2 + 0) * WPK_MAT);
    const int4* sb = (const int4*)(wpk + ((size_t)(0 * NBLK + n) * 2 + 1) * WPK_MAT);
    for (int idx = t; idx < WPK_MAT / 8; idx += 256) {
      ((int4*)Wa)[idx] = sa[idx];
      ((int4*)Wb)[idx] = sb[idx];
    }
  }
  f32x4 acc[12];
#pragma unroll
  for (int nt = 0; nt < 12; ++nt) {
    float bv = bpk[n * 192 + nt * 16 + l15];
    acc[nt] = { bv, bv, bv, bv };
  }
  __syncthreads();

#pragma unroll
  for (int kk = 0; kk < 6; ++kk) {
    const int k0 = kk * 32 + lg * 8;
    short8 a = *(const short8*)&Xs[wid * 16 + l15][k0];
    const bool hi = (kk >= 3);
    const int k2 = hi ? k0 - 96 : k0;
#pragma unroll
    for (int nt = 0; nt < 12; ++nt) {
      int c = nt * 16 + l15;
      short8 bfr;
      if (nt < 6) {
        if (!hi) bfr = *(const short8*)&Wa[c][k2];
        else {
          int4 nb = *(const int4*)&Wb[c][k2];
          nb.x ^= 0x80008000; nb.y ^= 0x80008000; nb.z ^= 0x80008000; nb.w ^= 0x80008000;
          bfr = __builtin_bit_cast(short8, nb);
        }
      } else {
        bfr = hi ? *(const short8*)&Wa[c - 96][k2] : *(const short8*)&Wb[c - 96][k2];
      }
      acc[nt] = __builtin_amdgcn_mfma_f32_16x16x32_bf16(a, bfr, acc[nt], 0, 0, 0);
    }
  }

#pragma unroll
  for (int nt = 0; nt < 12; ++nt) {
    int orow = wid * 16 + lg * 4, oc = nt * 16 + l15;
#pragma unroll
    for (int r = 0; r < 4; ++r)
      Xs[orow + r][oc] = f2bf(fmaxf(acc[nt][r], 0.f));
  }
  __syncthreads();
  {
    const int4* sa = (const int4*)(wpk + ((size_t)(1 * NBLK + n) * 2 + 0) * WPK_MAT);
    const int4* sb = (const int4*)(wpk + ((size_t)(1 * NBLK + n) * 2 + 1) * WPK_MAT);
    for (int idx = t; idx < WPK_MAT / 8; idx += 256) {
      ((int4*)Wa)[idx] = sa[idx];
      ((int4*)Wb)[idx] = sb[idx];
    }
  }
#pragma unroll
  for (int nt = 0; nt < 12; ++nt) {
    float bv = bpk[(NBLK + n) * 192 + nt * 16 + l15];
    acc[nt] = { bv, bv, bv, bv };
  }
  __syncthreads();

#pragma unroll
  for (int kk = 0; kk < 6; ++kk) {
    const int k0 = kk * 32 + lg * 8;
    short8 a = *(const short8*)&Xs[wid * 16 + l15][k0];
    const bool hi = (kk >= 3);
    const int k2 = hi ? k0 - 96 : k0;
#pragma unroll
    for (int nt = 0; nt < 12; ++nt) {
      int c = nt * 16 + l15;
      short8 bfr;
      if (nt < 6) {
        if (!hi) bfr = *(const short8*)&Wa[c][k2];
        else {
          int4 nb = *(const int4*)&Wb[c][k2];
          nb.x ^= 0x80008000; nb.y ^= 0x80008000; nb.z ^= 0x80008000; nb.w ^= 0x80008000;
          bfr = __builtin_bit_cast(short8, nb);
        }
      } else {
        bfr = hi ? *(const short8*)&Wa[c - 96][k2] : *(const short8*)&Wb[c - 96][k2];
      }
      acc[nt] = __builtin_amdgcn_mfma_f32_16x16x32_bf16(a, bfr, acc[nt], 0, 0, 0);
    }
  }

#pragma unroll
  for (int r = 0; r < 4; ++r) {
    int p = p0 + wid * 16 + lg * 4 + r;
    int ku = p / WC, kv = p - ku * WC;
    float kus = (ku >= 64) ? (float)(ku - 128) : (float)ku;
    float k2v = kus * kus + (float)(kv * kv);
    float thr = fmaxf(0.01f * expf(-0.00125f * k2v), 0.0005f);
#pragma unroll
    for (int nt = 0; nt < 6; ++nt) {
      float mr = acc[nt][r], mi = acc[nt + 6][r];
      float mag = sqrtf(mr * mr + mi * mi + 1e-8f);
      float sf = fmaxf(mag - thr, 0.f) / mag;
      size_t g = ((size_t)b * NPOS + p) * HD + n * BLKC + nt * 16 + l15;
      A[g] = pack2(mr * sf, mi * sf);
    }
  }
}

extern "C" void kernel_launch(void* const* d_in, const int* in_sizes, int n_in,
                              void* d_out, int out_size, void* d_ws, size_t ws_size,
                              hipStream_t stream) {
  const float* x  = (const float*)d_in[0];
  const float* w1 = (const float*)d_in[1];
  const float* b1 = (const float*)d_in[2];
  const float* w2 = (const float*)d_in[3];
  const float* b2 = (const float*)d_in[4];
  float* out = (float*)d_out;
  unsigned int* A = (unsigned int*)d_ws;   // 4 * 8320 * 768 * 4B = 102.2 MB

  // packed weights in the tail of d_out; k_ifft_w overwrites them only after
  // the last k_mlp2 weight read (same-stream ordering).
  float* tail = out + ((size_t)out_size - TAIL_F32);
  unsigned short* wpk = (unsigned short*)tail;
  float* bpk = tail + WPK_F32;

  k_prep<<<16, 256, 0, stream>>>(w1, b1, w2, b2, wpk, bpk);
  k_fft_w<<<dim3(HH, HD / 32, 4), 256, 0, stream>>>(x, A);
  k_fft_h<-1><<<dim3(WC, HD / 32, 4), 256, 0, stream>>>(A);
  k_mlp2<<<dim3(NPOS / 64, NBLK, 4), 256, 0, stream>>>(A, wpk, bpk);
  k_fft_h<1><<<dim3(WC, HD / 32, 4), 256, 0, stream>>>(A);
  k_ifft_w<<<dim3(HH, HD / 32, 4), 256, 0, stream>>>(A, x, out);
}

// Round 5
// 563.176 us; speedup vs baseline: 12.7297x; 1.1188x over previous
//
#include <hip/hip_runtime.h>
#include <hip/hip_bf16.h>
#include <math.h>

// AFNO2D: rfft2(128x128, ortho) -> blockdiag complex MLP (8 x 96, MFMA bf16) -> softshrink
//         -> irfft2 -> +bias.  B=4, H=W=128, C=768.
// Spectral plane in ws: ONE packed uint per point (bf16 re | bf16 im << 16), A[b][pos][c],
// pos = h*65+kw. Three pipeline kernels:
//   k_fft_w : x -> A  (rfft along W, bins 0..64)
//   k_mid   : fftH-fwd + complex MLP + softshrink + fftH-inv, fully fused in LDS, in-place on A
//   k_ifft_w: A -> out (irfft along W, numpy c2r semantics) + bias
// All LDS tiles are [point][channel] with lanes iterating channel-fastest => <=2-way banks.
// MLP B-operands are pre-baked per-lane fragment images (conflict-free ds_read_b128).

#define HD   768
#define NBLK 8
#define HH   128
#define WW   128
#define WC   65
#define NPOS (HH * WC)

constexpr float SC    = 0.08838834764831845f;      // 1/sqrt(128)
constexpr float TWOPI = 6.28318530717958647692f;

constexpr int FRAGS_PER_MAT = 6 * 12;              // kk x nt
constexpr int WF_MAT_U16    = FRAGS_PER_MAT * 512; // 36864 ushorts per (layer, block)
constexpr int WF_U16        = 16 * WF_MAT_U16;     // 589824
constexpr int TAIL_F32      = 524288;              // 2MB tail of d_out for packed weights

typedef __attribute__((ext_vector_type(8))) short short8;
typedef __attribute__((ext_vector_type(4))) float f32x4;

static __device__ inline unsigned short f2bf(float f) {
  __hip_bfloat16 h = __float2bfloat16(f);
  return __builtin_bit_cast(unsigned short, h);
}
static __device__ inline unsigned int pack2(float re, float im) {
  return (unsigned int)f2bf(re) | ((unsigned int)f2bf(im) << 16);
}
static __device__ inline float lo2f(unsigned int u) {
  return __builtin_bit_cast(float, u << 16);
}
static __device__ inline float hi2f(unsigned int u) {
  return __builtin_bit_cast(float, u & 0xffff0000u);
}

// digit-reversed index for DIF passes radix 4,4,4,2: row p holds bin revidx(p)
static __device__ inline int revidx(int p) {
  return ((p >> 5) & 3) | (((p >> 3) & 3) << 2) | (((p >> 1) & 3) << 4) | ((p & 1) << 6);
}

static __device__ inline void fill_tab(float* ct, float* st, int t) {
  if (t < 128) {
    float s, c;
    sincosf((TWOPI / 128.f) * t, &s, &c);
    ct[t] = c; st[t] = s;
  }
}

// ---- forward DIF radix-4 pass on packed-bf16 complex LDS, layout Z[point*ZSTR + ch]
template <int SIGN, int S, int Q, int STEP, int NL, int ZSTR, int NTHR>
static __device__ inline void pass4p(unsigned int* Z, const float* ct, const float* st, int t) {
  for (int idx = t; idx < NL * 32; idx += NTHR) {
    int ch = idx % NL, gg = idx / NL;
    int seg = gg / Q, j = gg - seg * Q;
    int b0 = seg * S + j;
    unsigned int u0 = Z[(b0        ) * ZSTR + ch];
    unsigned int u1 = Z[(b0 +     Q) * ZSTR + ch];
    unsigned int u2 = Z[(b0 + 2 * Q) * ZSTR + ch];
    unsigned int u3 = Z[(b0 + 3 * Q) * ZSTR + ch];
    float x0r = lo2f(u0), x0i = hi2f(u0), x1r = lo2f(u1), x1i = hi2f(u1);
    float x2r = lo2f(u2), x2i = hi2f(u2), x3r = lo2f(u3), x3i = hi2f(u3);
    float apr = x0r + x2r, api = x0i + x2i;
    float amr = x0r - x2r, ami = x0i - x2i;
    float bpr = x1r + x3r, bpi = x1i + x3i;
    float bmr = x1r - x3r, bmi = x1i - x3i;
    float u0r = apr + bpr, u0i = api + bpi;
    float u2r = apr - bpr, u2i = api - bpi;
    float u1r, u1i, u3r, u3i;
    if constexpr (SIGN < 0) { u1r = amr + bmi; u1i = ami - bmr; u3r = amr - bmi; u3i = ami + bmr; }
    else                    { u1r = amr - bmi; u1i = ami + bmr; u3r = amr + bmi; u3i = ami - bmr; }
    int i1 = (j * STEP) & 127, i2 = (2 * j * STEP) & 127, i3 = (3 * j * STEP) & 127;
    float c1 = ct[i1], s1 = st[i1], c2 = ct[i2], s2 = st[i2], c3 = ct[i3], s3 = st[i3];
    float v1r, v1i, v2r, v2i, v3r, v3i;
    if constexpr (SIGN < 0) {
      v1r = u1r * c1 + u1i * s1; v1i = u1i * c1 - u1r * s1;
      v2r = u2r * c2 + u2i * s2; v2i = u2i * c2 - u2r * s2;
      v3r = u3r * c3 + u3i * s3; v3i = u3i * c3 - u3r * s3;
    } else {
      v1r = u1r * c1 - u1i * s1; v1i = u1i * c1 + u1r * s1;
      v2r = u2r * c2 - u2i * s2; v2i = u2i * c2 + u2r * s2;
      v3r = u3r * c3 - u3i * s3; v3i = u3i * c3 + u3r * s3;
    }
    Z[(b0        ) * ZSTR + ch] = pack2(u0r, u0i);
    Z[(b0 +     Q) * ZSTR + ch] = pack2(v1r, v1i);
    Z[(b0 + 2 * Q) * ZSTR + ch] = pack2(v2r, v2i);
    Z[(b0 + 3 * Q) * ZSTR + ch] = pack2(v3r, v3i);
  }
}

// ---- radix-2 pass (self-inverse butterfly; used as last fwd pass and first inverse pass)
template <int NL, int ZSTR, int NTHR, bool SCALE>
static __device__ inline void r2p(unsigned int* Z, int t) {
  for (int idx = t; idx < NL * 64; idx += NTHR) {
    int ch = idx % NL, g = idx / NL;
    int b0 = 2 * g;
    unsigned int ua = Z[b0 * ZSTR + ch], ub = Z[(b0 + 1) * ZSTR + ch];
    float ar = lo2f(ua), ai = hi2f(ua), br = lo2f(ub), bi = hi2f(ub);
    float s = SCALE ? SC : 1.f;
    Z[b0 * ZSTR + ch]       = pack2((ar + br) * s, (ai + bi) * s);
    Z[(b0 + 1) * ZSTR + ch] = pack2((ar - br) * s, (ai - bi) * s);
  }
}

// ---- inverse DIT radix-4 pass: exact inverse of pass4p<-1,S,Q,STEP> (conj twiddle first,
//      then inverse DFT4 with +i). Consumes digit-reversed data in place.
template <int S, int Q, int STEP, int NL, int ZSTR, int NTHR, bool SCALE>
static __device__ inline void ipass4p(unsigned int* Z, const float* ct, const float* st, int t) {
  for (int idx = t; idx < NL * 32; idx += NTHR) {
    int ch = idx % NL, gg = idx / NL;
    int seg = gg / Q, j = gg - seg * Q;
    int b0 = seg * S + j;
    unsigned int w0 = Z[(b0        ) * ZSTR + ch];
    unsigned int w1 = Z[(b0 +     Q) * ZSTR + ch];
    unsigned int w2 = Z[(b0 + 2 * Q) * ZSTR + ch];
    unsigned int w3 = Z[(b0 + 3 * Q) * ZSTR + ch];
    float y0r = lo2f(w0), y0i = hi2f(w0), y1r = lo2f(w1), y1i = hi2f(w1);
    float y2r = lo2f(w2), y2i = hi2f(w2), y3r = lo2f(w3), y3i = hi2f(w3);
    int i1 = (j * STEP) & 127, i2 = (2 * j * STEP) & 127, i3 = (3 * j * STEP) & 127;
    float c1 = ct[i1], s1 = st[i1], c2 = ct[i2], s2 = st[i2], c3 = ct[i3], s3 = st[i3];
    // u_m = y_m * (c + i s)
    float u1r = y1r * c1 - y1i * s1, u1i = y1i * c1 + y1r * s1;
    float u2r = y2r * c2 - y2i * s2, u2i = y2i * c2 + y2r * s2;
    float u3r = y3r * c3 - y3i * s3, u3i = y3i * c3 + y3r * s3;
    float pr = y0r + u2r, pi = y0i + u2i, mr = y0r - u2r, mi = y0i - u2i;
    float qr = u1r + u3r, qi = u1i + u3i, dr = u1r - u3r, di = u1i - u3i;
    float s_ = SCALE ? SC : 1.f;
    Z[(b0        ) * ZSTR + ch] = pack2((pr + qr) * s_, (pi + qi) * s_);
    Z[(b0 +     Q) * ZSTR + ch] = pack2((mr - di) * s_, (mi + dr) * s_);
    Z[(b0 + 2 * Q) * ZSTR + ch] = pack2((pr - qr) * s_, (pi - qi) * s_);
    Z[(b0 + 3 * Q) * ZSTR + ch] = pack2((mr + di) * s_, (mi - dr) * s_);
  }
}

// ================= stage 1: rfft along W, x -> packed A (bins 0..64)
#define FW_STR 68
__global__ __launch_bounds__(256) void k_fft_w(const float* __restrict__ x,
                                               unsigned int* __restrict__ A) {
  __shared__ unsigned int Zw[128 * FW_STR];
  __shared__ float ct[128], st[128];
  const int h = blockIdx.x, c0 = blockIdx.y * 64, b = blockIdx.z, t = threadIdx.x;
  fill_tab(ct, st, t);
  const float* xp = x + ((size_t)(b * HH + h)) * WW * HD + c0;
  for (int idx = t; idx < 128 * 64; idx += 256) {
    int w = idx >> 6, ch = idx & 63;
    Zw[w * FW_STR + ch] = (unsigned int)f2bf(xp[(size_t)w * HD + ch]);  // im = 0
  }
  __syncthreads();
  pass4p<-1, 128, 32, 1, 64, FW_STR, 256>(Zw, ct, st, t); __syncthreads();
  pass4p<-1, 32, 8, 4, 64, FW_STR, 256>(Zw, ct, st, t);   __syncthreads();
  pass4p<-1, 8, 2, 16, 64, FW_STR, 256>(Zw, ct, st, t);   __syncthreads();
  r2p<64, FW_STR, 256, false>(Zw, t);                     __syncthreads();
  unsigned int* Ao = A + ((size_t)b * NPOS + h * WC) * HD + c0;
  for (int idx = t; idx < 128 * 64; idx += 256) {
    int p = idx >> 6, ch = idx & 63;
    int k = revidx(p);
    if (k < WC) {
      unsigned int u = Zw[p * FW_STR + ch];
      Ao[(size_t)k * HD + ch] = pack2(lo2f(u) * SC, hi2f(u) * SC);
    }
  }
}

// ================= stage 5: irfft along W (imag of bins 0,64 ignored) + bias
__global__ __launch_bounds__(256) void k_ifft_w(const unsigned int* __restrict__ A,
                                                const float* __restrict__ x,
                                                float* __restrict__ out) {
  __shared__ unsigned int Zw[128 * FW_STR];
  __shared__ float ct[128], st[128];
  const int h = blockIdx.x, c0 = blockIdx.y * 64, b = blockIdx.z, t = threadIdx.x;
  fill_tab(ct, st, t);
  const unsigned int* Ai = A + ((size_t)b * NPOS + h * WC) * HD + c0;
  for (int idx = t; idx < WC * 64; idx += 256) {
    int k = idx >> 6, ch = idx & 63;
    unsigned int u = Ai[(size_t)k * HD + ch];
    if (k == 0 || k == 64) u &= 0xffffu;          // numpy c2r: drop imag
    Zw[k * FW_STR + ch] = u;
  }
  __syncthreads();
  for (int idx = t; idx < 63 * 64; idx += 256) {  // Hermitian mirror 65..127
    int k = 65 + (idx >> 6), ch = idx & 63;
    Zw[k * FW_STR + ch] = Zw[(128 - k) * FW_STR + ch] ^ 0x80000000u;  // conj
  }
  __syncthreads();
  pass4p<1, 128, 32, 1, 64, FW_STR, 256>(Zw, ct, st, t); __syncthreads();
  pass4p<1, 32, 8, 4, 64, FW_STR, 256>(Zw, ct, st, t);   __syncthreads();
  pass4p<1, 8, 2, 16, 64, FW_STR, 256>(Zw, ct, st, t);   __syncthreads();
  r2p<64, FW_STR, 256, false>(Zw, t);                    __syncthreads();
  const size_t rowbase = ((size_t)(b * HH + h)) * WW * HD + c0;
  for (int idx = t; idx < 128 * 64; idx += 256) {
    int p = idx >> 6, ch = idx & 63;
    int w = revidx(p);
    size_t go = rowbase + (size_t)w * HD + ch;
    out[go] = fmaf(lo2f(Zw[p * FW_STR + ch]), SC, x[go]);
  }
}

// ================= weight prep: bake per-lane MFMA B-fragment images + augmented biases
__global__ __launch_bounds__(256) void k_prep(const float* __restrict__ w1,
                                              const float* __restrict__ b1,
                                              const float* __restrict__ w2,
                                              const float* __restrict__ b2,
                                              unsigned short* __restrict__ wf,
                                              float* __restrict__ bpk) {
  const int l = blockIdx.x >> 3, n = blockIdx.x & 7;
  const float* w  = l ? w2 : w1;
  const float* bs = l ? b2 : b1;
  unsigned short* dst = wf + (size_t)blockIdx.x * WF_MAT_U16;
  for (int idx = threadIdx.x; idx < WF_MAT_U16; idx += 256) {
    int frag = idx >> 9, lanej = idx & 511;
    int lane = lanej >> 3, j = lanej & 7;
    int kk = frag / 12, nt = frag - kk * 12;
    int lg = lane >> 4, l15 = lane & 15;
    int k = kk * 32 + lg * 8 + j;
    int cc = nt * 16 + l15;
    bool hi = k >= 96;
    int k2 = hi ? k - 96 : k;
    int o = (cc < 96) ? cc : cc - 96;
    float v;
    if (cc < 96) v = hi ? -w[(size_t)(8 + n) * 9216 + k2 * 96 + o] : w[(size_t)n * 9216 + k2 * 96 + o];
    else         v = hi ?  w[(size_t)n * 9216 + k2 * 96 + o]       : w[(size_t)(8 + n) * 9216 + k2 * 96 + o];
    dst[idx] = f2bf(v);
  }
  for (int c = threadIdx.x; c < 192; c += 256)
    bpk[blockIdx.x * 192 + c] = (c < 96) ? bs[n * 96 + c] : bs[(8 + n) * 96 + (c - 96)];
}

// ================= fused middle: fftH-fwd + MLP + softshrink + fftH-inv, in-place on A
#define ZSTRM 100
static __device__ inline short8 afrag(const unsigned int* Zp, int row, int k0) {
  unsigned int r0, r1, r2, r3;
  if (k0 < 96) {
    const unsigned int* z = Zp + row * ZSTRM + k0;
    uint4 a = *(const uint4*)z, c = *(const uint4*)(z + 4);
    r0 = (a.x & 0xffffu) | (a.y << 16);
    r1 = (a.z & 0xffffu) | (a.w << 16);
    r2 = (c.x & 0xffffu) | (c.y << 16);
    r3 = (c.z & 0xffffu) | (c.w << 16);
  } else {
    const unsigned int* z = Zp + row * ZSTRM + (k0 - 96);
    uint4 a = *(const uint4*)z, c = *(const uint4*)(z + 4);
    r0 = (a.x >> 16) | (a.y & 0xffff0000u);
    r1 = (a.z >> 16) | (a.w & 0xffff0000u);
    r2 = (c.x >> 16) | (c.y & 0xffff0000u);
    r3 = (c.z >> 16) | (c.w & 0xffff0000u);
  }
  uint4 rr = { r0, r1, r2, r3 };
  return __builtin_bit_cast(short8, rr);
}

__global__ __launch_bounds__(512) void k_mid(unsigned int* __restrict__ A,
                                             const unsigned short* __restrict__ wf,
                                             const float* __restrict__ bpk) {
  __shared__ unsigned int Zp[128 * ZSTRM];       // [row(ku)][ch] packed bf16 re|im
  __shared__ unsigned short WfL[WF_MAT_U16];     // one layer's baked B-fragments
  __shared__ float ct[128], st[128];
  const int kv = blockIdx.x, n = blockIdx.y, b = blockIdx.z, t = threadIdx.x;
  fill_tab(ct, st, t);
  unsigned int* Abase = A + ((size_t)b * NPOS + kv) * HD + n * 96;

  for (int idx = t; idx < 128 * 96; idx += 512) {
    int r = idx / 96, ch = idx - r * 96;
    Zp[r * ZSTRM + ch] = Abase[(size_t)r * WC * HD + ch];
  }
  {
    const int4* src = (const int4*)(wf + (size_t)n * WF_MAT_U16);
    for (int idx = t; idx < WF_MAT_U16 / 8; idx += 512) ((int4*)WfL)[idx] = src[idx];
  }
  __syncthreads();

  // forward FFT along rows (lines = 96 channels), SC folded into last pass
  pass4p<-1, 128, 32, 1, 96, ZSTRM, 512>(Zp, ct, st, t); __syncthreads();
  pass4p<-1, 32, 8, 4, 96, ZSTRM, 512>(Zp, ct, st, t);   __syncthreads();
  pass4p<-1, 8, 2, 16, 96, ZSTRM, 512>(Zp, ct, st, t);   __syncthreads();
  r2p<96, ZSTRM, 512, true>(Zp, t);                      __syncthreads();

  const int wid = t >> 6, lane = t & 63, l15 = lane & 15, lg = lane >> 4;
  const int row = wid * 16 + l15;

  f32x4 acc[12];
#pragma unroll
  for (int nt = 0; nt < 12; ++nt) {
    float bv = bpk[n * 192 + nt * 16 + l15];
    acc[nt] = { bv, bv, bv, bv };
  }
  // ---- layer 1
#pragma unroll
  for (int kk = 0; kk < 6; ++kk) {
    short8 a = afrag(Zp, row, kk * 32 + lg * 8);
#pragma unroll
    for (int nt = 0; nt < 12; ++nt) {
      short8 bfr = *(const short8*)&WfL[(kk * 12 + nt) * 512 + lane * 8];
      acc[nt] = __builtin_amdgcn_mfma_f32_16x16x32_bf16(a, bfr, acc[nt], 0, 0, 0);
    }
  }
  // relu -> O1 packed back into own strip rows of Zp
#pragma unroll
  for (int nt = 0; nt < 6; ++nt) {
    int orow = wid * 16 + lg * 4, oc = nt * 16 + l15;
#pragma unroll
    for (int r = 0; r < 4; ++r)
      Zp[(orow + r) * ZSTRM + oc] =
          pack2(fmaxf(acc[nt][r], 0.f), fmaxf(acc[nt + 6][r], 0.f));
  }
  __syncthreads();
  {
    const int4* src = (const int4*)(wf + (size_t)(8 + n) * WF_MAT_U16);
    for (int idx = t; idx < WF_MAT_U16 / 8; idx += 512) ((int4*)WfL)[idx] = src[idx];
  }
#pragma unroll
  for (int nt = 0; nt < 12; ++nt) {
    float bv = bpk[(8 + n) * 192 + nt * 16 + l15];
    acc[nt] = { bv, bv, bv, bv };
  }
  __syncthreads();
  // ---- layer 2
#pragma unroll
  for (int kk = 0; kk < 6; ++kk) {
    short8 a = afrag(Zp, row, kk * 32 + lg * 8);
#pragma unroll
    for (int nt = 0; nt < 12; ++nt) {
      short8 bfr = *(const short8*)&WfL[(kk * 12 + nt) * 512 + lane * 8];
      acc[nt] = __builtin_amdgcn_mfma_f32_16x16x32_bf16(a, bfr, acc[nt], 0, 0, 0);
    }
  }
  // softshrink (bin = revidx(row)) + packed write into own rows
#pragma unroll
  for (int r = 0; r < 4; ++r) {
    int p = wid * 16 + lg * 4 + r;
    int ku = revidx(p);
    float kus = (ku >= 64) ? (float)(ku - 128) : (float)ku;
    float k2v = kus * kus + (float)(kv * kv);
    float thr = fmaxf(0.01f * expf(-0.00125f * k2v), 0.0005f);
#pragma unroll
    for (int nt = 0; nt < 6; ++nt) {
      float mr = acc[nt][r], mi = acc[nt + 6][r];
      float mag = sqrtf(mr * mr + mi * mi + 1e-8f);
      float sf = fmaxf(mag - thr, 0.f) / mag;
      Zp[p * ZSTRM + nt * 16 + l15] = pack2(mr * sf, mi * sf);
    }
  }
  __syncthreads();

  // inverse FFT (DIT; consumes digit-reversed rows, natural output), SC in last pass
  r2p<96, ZSTRM, 512, false>(Zp, t);                      __syncthreads();
  ipass4p<8, 2, 16, 96, ZSTRM, 512, false>(Zp, ct, st, t); __syncthreads();
  ipass4p<32, 8, 4, 96, ZSTRM, 512, false>(Zp, ct, st, t); __syncthreads();
  ipass4p<128, 32, 1, 96, ZSTRM, 512, true>(Zp, ct, st, t); __syncthreads();

  for (int idx = t; idx < 128 * 96; idx += 512) {
    int r = idx / 96, ch = idx - r * 96;
    Abase[(size_t)r * WC * HD + ch] = Zp[r * ZSTRM + ch];
  }
}

extern "C" void kernel_launch(void* const* d_in, const int* in_sizes, int n_in,
                              void* d_out, int out_size, void* d_ws, size_t ws_size,
                              hipStream_t stream) {
  const float* x  = (const float*)d_in[0];
  const float* w1 = (const float*)d_in[1];
  const float* b1 = (const float*)d_in[2];
  const float* w2 = (const float*)d_in[3];
  const float* b2 = (const float*)d_in[4];
  float* out = (float*)d_out;
  unsigned int* A = (unsigned int*)d_ws;          // 4 * 8320 * 768 * 4B = 102.2 MB

  // baked weights live in the tail 2MB of d_out; k_ifft_w (which never reads them)
  // overwrites that region only after k_mid finished (same-stream ordering).
  float* tail = out + ((size_t)out_size - TAIL_F32);
  unsigned short* wf = (unsigned short*)tail;
  float* bpk = tail + WF_U16 / 2;

  k_prep<<<16, 256, 0, stream>>>(w1, b1, w2, b2, wf, bpk);
  k_fft_w<<<dim3(HH, HD / 64, 4), 256, 0, stream>>>(x, A);
  k_mid<<<dim3(WC, NBLK, 4), 512, 0, stream>>>(A, wf, bpk);
  k_ifft_w<<<dim3(HH, HD / 64, 4), 256, 0, stream>>>(A, x, out);
}

// Round 7
// 454.302 us; speedup vs baseline: 15.7803x; 1.2396x over previous
//
#include <hip/hip_runtime.h>
#include <hip/hip_bf16.h>
#include <math.h>

// AFNO2D: rfft2(128x128, ortho) -> blockdiag complex MLP (8 x 96) -> softshrink -> irfft2 -> +bias
// B=4, H=W=128, C=768.  ALL transforms are MFMA GEMMs against baked bf16 DFT matrices.
// Spectral plane in ws: packed uint per point (bf16 re | bf16 im<<16), A[b][pos=h*65+kw][c].
// Baked fragment tables live in d_ws DIRECTLY AFTER the A plane (nothing else writes there;
// round-6 bug was putting them in the d_out tail, which k_ifft_w itself overwrites -> race -> NaN).
// Kernels: k_prep (bake frags) ; k_fft_w (x->A) ; k_mid (H-DFT fwd + MLP + shrink + H-DFT inv,
// fused, in-place) ; k_ifft_w (A->out, numpy c2r semantics, +bias).

#define HD   768
#define NBLK 8
#define HH   128
#define WW   128
#define WC   65
#define NPOS (HH * WC)

constexpr float SC    = 0.08838834764831845f;      // 1/sqrt(128)
constexpr float TWOPI = 6.28318530717958647692f;

// table layout (ushort offsets from wf base)
constexpr int TM_OFF     = 0;        // H-DFT: 256 frags = dir(2) x part(2) x kot(8) x kk(8)
constexpr int TW_OFF     = 131072;   // W-rfft: 40 frags = mt(10) x kk(4)
constexpr int TWI_OFF    = 151552;   // W-irfft: 40 frags = mt(8) x kk(5)
constexpr int WF_OFF     = 172032;   // MLP: 16 (layer,n) x 36 frags (dedup kk 0..2)
constexpr int WF_END_U16 = 466944;   // WF_OFF + 16*36*512
constexpr size_t A_UINTS = (size_t)4 * NPOS * HD;  // 25,559,040 uints = 102.2 MB

typedef __attribute__((ext_vector_type(8))) short short8;
typedef __attribute__((ext_vector_type(4))) float f32x4;

#define MFMA __builtin_amdgcn_mfma_f32_16x16x32_bf16

static __device__ inline unsigned short f2bf(float f) {
  __hip_bfloat16 h = __float2bfloat16(f);
  return __builtin_bit_cast(unsigned short, h);
}
static __device__ inline unsigned int pack2(float re, float im) {
  return (unsigned int)f2bf(re) | ((unsigned int)f2bf(im) << 16);
}
// build short8 from lo/hi bf16 halves of 8 packed uints
static __device__ inline short8 lo8(uint4 a, uint4 b) {
  uint4 r = { (a.x & 0xffffu) | (a.y << 16), (a.z & 0xffffu) | (a.w << 16),
              (b.x & 0xffffu) | (b.y << 16), (b.z & 0xffffu) | (b.w << 16) };
  return __builtin_bit_cast(short8, r);
}
static __device__ inline short8 hi8(uint4 a, uint4 b) {
  uint4 r = { (a.x >> 16) | (a.y & 0xffff0000u), (a.z >> 16) | (a.w & 0xffff0000u),
              (b.x >> 16) | (b.y & 0xffff0000u), (b.z >> 16) | (b.w & 0xffff0000u) };
  return __builtin_bit_cast(short8, r);
}

// ================= k_prep: bake all MFMA fragment images =================
// A-frag: lane holds A[row = tile*16 + (l&15)][k = kk*32 + (l>>4)*8 + j]
// B-frag: lane holds B[k = kk*32 + (l>>4)*8 + j][col = nt*16 + (l&15)]
__global__ __launch_bounds__(256) void k_prep(const float* __restrict__ w1,
                                              const float* __restrict__ b1,
                                              const float* __restrict__ w2,
                                              const float* __restrict__ b2,
                                              unsigned short* __restrict__ wf,
                                              float* __restrict__ bpk) {
  const int blk = blockIdx.x, t = threadIdx.x;
  if (blk < 16) {                      // MLP weight frags (dedup: kk 0..2 only) + biases
    const int layer = blk >> 3, n = blk & 7;
    const float* w  = layer ? w2 : w1;
    const float* bs = layer ? b2 : b1;
    unsigned short* dst = wf + WF_OFF + (size_t)blk * (36 * 512);
    for (int e = t; e < 36 * 512; e += 256) {
      int f = e >> 9, idx = e & 511;
      int kk = f / 12, nt = f - kk * 12;
      int lane = idx >> 3, j = idx & 7;
      int k = kk * 32 + (lane >> 4) * 8 + j;      // < 96
      int cc = nt * 16 + (lane & 15);
      float v = (cc < 96) ? w[(size_t)n * 9216 + k * 96 + cc]
                          : w[(size_t)(8 + n) * 9216 + k * 96 + (cc - 96)];
      dst[e] = f2bf(v);
    }
    for (int c = t; c < 192; c += 256)
      bpk[blk * 192 + c] = (c < 96) ? bs[n * 96 + c] : bs[(8 + n) * 96 + (c - 96)];
  } else if (blk < 18) {               // H-DFT twiddles (A-operand), fwd & inv, x SC
    const int base = (blk - 16) * 128;
    for (int e = t; e < 128 * 512; e += 256) {
      int f = base + (e >> 9), idx = e & 511;
      int dir = f >> 7, part = (f >> 6) & 1, kot = (f >> 3) & 7, kk = f & 7;
      int lane = idx >> 3, j = idx & 7;
      int ko = kot * 16 + (lane & 15);
      int k  = kk * 32 + (lane >> 4) * 8 + j;     // 0..255 (re-half | im-half)
      int r  = k & 127;
      float sn, cs; sincosf((TWOPI / 128.f) * (float)((ko * r) & 127), &sn, &cs);
      float v;
      if (dir == 0) v = part ? (k < 128 ? -sn : cs) : (k < 128 ? cs : sn);
      else          v = part ? (k < 128 ?  sn : cs) : (k < 128 ? cs : -sn);
      wf[TM_OFF + (size_t)f * 512 + idx] = f2bf(v * SC);
    }
  } else if (blk == 18) {              // W-rfft matrix: rows 0..79 = re, 80..159 = im
    for (int e = t; e < 40 * 512; e += 256) {
      int f = e >> 9, idx = e & 511;
      int mt = f >> 2, kk = f & 3;
      int lane = idx >> 3, j = idx & 7;
      int row = mt * 16 + (lane & 15);
      int r   = kk * 32 + (lane >> 4) * 8 + j;    // 0..127
      int kor = (row < 80) ? row : row - 80;
      float sn, cs; sincosf((TWOPI / 128.f) * (float)((kor * r) & 127), &sn, &cs);
      wf[TW_OFF + (size_t)f * 512 + idx] = f2bf((row < 80 ? cs : -sn) * SC);
    }
  } else {                             // W-irfft matrix: K = [re 0..79 | im 0..79]
    for (int e = t; e < 40 * 512; e += 256) {
      int f = e >> 9, idx = e & 511;
      int mt = f / 5, kk = f - mt * 5;
      int lane = idx >> 3, j = idx & 7;
      int wr = mt * 16 + (lane & 15);
      int k  = kk * 32 + (lane >> 4) * 8 + j;     // 0..159
      float v = 0.f;
      if (k < 80) {
        int kb = k;
        if (kb <= 64) {
          float sn, cs; sincosf((TWOPI / 128.f) * (float)((wr * kb) & 127), &sn, &cs);
          v = SC * ((kb == 0 || kb == 64) ? 1.f : 2.f) * cs;
        }
      } else {
        int kb = k - 80;                           // imag of bins 0,64 ignored (c2r)
        if (kb >= 1 && kb <= 63) {
          float sn, cs; sincosf((TWOPI / 128.f) * (float)((wr * kb) & 127), &sn, &cs);
          v = -2.f * SC * sn;
        }
      }
      wf[TWI_OFF + (size_t)f * 512 + idx] = f2bf(v);
    }
  }
}

// ================= k_fft_w: rfft along W via GEMM, x -> packed A =================
__global__ __launch_bounds__(256) void k_fft_w(const float* __restrict__ x,
                                               unsigned int* __restrict__ A,
                                               const unsigned short* __restrict__ wf) {
  __shared__ unsigned short Xt[64 * 136];          // [ch][r] bf16, stride 136 (16B-aligned)
  const int h = blockIdx.x, c0 = blockIdx.y * 64, b = blockIdx.z, t = threadIdx.x;
  const int wv = t >> 6, lane = t & 63, l15 = lane & 15, lg = lane >> 4;
  const float* xp = x + ((size_t)(b * HH + h)) * WW * HD + c0;
  for (int idx = t; idx < 128 * 64; idx += 256) {
    int r = idx >> 6, ch = idx & 63;
    Xt[ch * 136 + r] = f2bf(xp[(size_t)r * HD + ch]);
  }
  __syncthreads();
  const unsigned short* tw = wf + TW_OFF;
  f32x4 acc[10];
#pragma unroll
  for (int m = 0; m < 10; ++m) acc[m] = { 0.f, 0.f, 0.f, 0.f };
#pragma unroll
  for (int kk = 0; kk < 4; ++kk) {
    short8 bq = *(const short8*)&Xt[(wv * 16 + l15) * 136 + kk * 32 + lg * 8];
#pragma unroll
    for (int m = 0; m < 10; ++m) {
      short8 a = *(const short8*)&tw[(size_t)(m * 4 + kk) * 512 + lane * 8];
      acc[m] = MFMA(a, bq, acc[m], 0, 0, 0);
    }
  }
  unsigned int* Ao = A + ((size_t)b * NPOS + h * WC) * HD + c0 + wv * 16 + l15;
#pragma unroll
  for (int q = 0; q < 5; ++q)
#pragma unroll
    for (int r = 0; r < 4; ++r) {
      int ko = q * 16 + lg * 4 + r;
      if (ko <= 64) Ao[(size_t)ko * HD] = pack2(acc[q][r], acc[5 + q][r]);
    }
}

// ================= k_ifft_w: irfft along W via GEMM + bias =================
__global__ __launch_bounds__(256) void k_ifft_w(const unsigned int* __restrict__ A,
                                                const float* __restrict__ x,
                                                float* __restrict__ out,
                                                const unsigned short* __restrict__ wf) {
  __shared__ unsigned short Zt[64 * 168];          // [ch][k-stack 160], stride 168
  const int h = blockIdx.x, c0 = blockIdx.y * 64, b = blockIdx.z, t = threadIdx.x;
  const int wv = t >> 6, lane = t & 63, l15 = lane & 15, lg = lane >> 4;
  const unsigned int* Ai = A + ((size_t)b * NPOS + h * WC) * HD + c0;
  for (int idx = t; idx < 65 * 64; idx += 256) {
    int kb = idx >> 6, ch = idx & 63;
    unsigned int u = Ai[(size_t)kb * HD + ch];
    Zt[ch * 168 + kb]      = (unsigned short)(u & 0xffffu);
    Zt[ch * 168 + 80 + kb] = (unsigned short)(u >> 16);
  }
  for (int idx = t; idx < 64 * 32; idx += 256) {   // zero-pad k 65..79 both halves
    int ch = idx >> 5, q = idx & 31;
    if (q < 30) {
      int kb = 65 + (q % 15), half = q / 15;
      Zt[ch * 168 + half * 80 + kb] = 0;
    }
  }
  __syncthreads();
  const unsigned short* twi = wf + TWI_OFF;
  f32x4 acc[8];
#pragma unroll
  for (int m = 0; m < 8; ++m) acc[m] = { 0.f, 0.f, 0.f, 0.f };
#pragma unroll
  for (int kk = 0; kk < 5; ++kk) {
    short8 bq = *(const short8*)&Zt[(wv * 16 + l15) * 168 + kk * 32 + lg * 8];
#pragma unroll
    for (int m = 0; m < 8; ++m) {
      short8 a = *(const short8*)&twi[(size_t)(m * 5 + kk) * 512 + lane * 8];
      acc[m] = MFMA(a, bq, acc[m], 0, 0, 0);
    }
  }
#pragma unroll
  for (int m = 0; m < 8; ++m)
#pragma unroll
    for (int r = 0; r < 4; ++r) {
      int wr = m * 16 + lg * 4 + r;
      size_t go = (((size_t)(b * HH + h)) * WW + wr) * HD + c0 + wv * 16 + l15;
      out[go] = acc[m][r] + x[go];
    }
}

// ================= k_mid: H-DFT fwd + MLP + softshrink + H-DFT inv =================
#define ZCS 132   // [ch][r] stride (uints)  - GEMM input layout
#define ZQS 100   // [pos][ch] stride (uints) - MLP layout

static __device__ inline short8 afragq(const unsigned int* Zq, int row, int k0) {
  const unsigned int* z = Zq + row * ZQS + (k0 < 96 ? k0 : k0 - 96);
  uint4 a = *(const uint4*)z, b = *(const uint4*)(z + 4);
  return (k0 < 96) ? lo8(a, b) : hi8(a, b);
}

// complex 128-DFT GEMM: A = baked twiddles (global), B = Zc[ch][r] packed (LDS).
template <int DIRBASE>
static __device__ inline void dft_gemm(const unsigned int* Zc, const unsigned short* tm,
                                       int w, int lane, f32x4* aR, f32x4* aI) {
  const int l15 = lane & 15, lg = lane >> 4;
#pragma unroll
  for (int kkr = 0; kkr < 4; ++kkr) {
    const int r0 = kkr * 32 + lg * 8;
    short8 aRlo = *(const short8*)&tm[(size_t)(DIRBASE + w * 8 + kkr) * 512 + lane * 8];
    short8 aRhi = *(const short8*)&tm[(size_t)(DIRBASE + w * 8 + kkr + 4) * 512 + lane * 8];
    short8 aIlo = *(const short8*)&tm[(size_t)(DIRBASE + 64 + w * 8 + kkr) * 512 + lane * 8];
    short8 aIhi = *(const short8*)&tm[(size_t)(DIRBASE + 64 + w * 8 + kkr + 4) * 512 + lane * 8];
#pragma unroll
    for (int co = 0; co < 6; ++co) {
      const unsigned int* z = Zc + (co * 16 + l15) * ZCS + r0;
      uint4 za = *(const uint4*)z;
      uint4 zb = *(const uint4*)(z + 4);
      short8 blo = lo8(za, zb);
      short8 bhi = hi8(za, zb);
      aR[co] = MFMA(aRlo, blo, aR[co], 0, 0, 0);
      aR[co] = MFMA(aRhi, bhi, aR[co], 0, 0, 0);
      aI[co] = MFMA(aIlo, blo, aI[co], 0, 0, 0);
      aI[co] = MFMA(aIhi, bhi, aI[co], 0, 0, 0);
    }
  }
}

__global__ __launch_bounds__(512) void k_mid(unsigned int* __restrict__ A,
                                             const unsigned short* __restrict__ wf,
                                             const float* __restrict__ bpk) {
  __shared__ unsigned int Zb[12800];               // 51.2 KB, layout morphs per phase
  __shared__ unsigned short WfL[36 * 512];         // 36.9 KB, one MLP layer's frags
  const int kv = blockIdx.x, n = blockIdx.y, b = blockIdx.z, t = threadIdx.x;
  const int wid = t >> 6, lane = t & 63, l15 = lane & 15, lg = lane >> 4;
  unsigned int* Abase = A + ((size_t)b * NPOS + kv) * HD + n * 96;
  const unsigned short* tm = wf + TM_OFF;

  // ---- stage: global -> Zc[ch][r]  +  layer-1 weight frags -> WfL
  for (int idx = t; idx < 128 * 96; idx += 512) {
    int r = idx / 96, ch = idx - r * 96;
    Zb[ch * ZCS + r] = Abase[(size_t)r * (WC * HD) + ch];
  }
  {
    const int4* src = (const int4*)(wf + WF_OFF + (size_t)n * (36 * 512));
    for (int idx = t; idx < 2304; idx += 512) ((int4*)WfL)[idx] = src[idx];
  }
  __syncthreads();

  // ---- GEMM-1: forward H-DFT (natural order out)
  f32x4 aR[6], aI[6];
#pragma unroll
  for (int co = 0; co < 6; ++co) { aR[co] = {0.f,0.f,0.f,0.f}; aI[co] = {0.f,0.f,0.f,0.f}; }
  dft_gemm<0>(Zb, tm, wid, lane, aR, aI);
  __syncthreads();                                  // all GEMM-1 reads done
#pragma unroll
  for (int co = 0; co < 6; ++co)                    // write back as Zq[pos][ch]
#pragma unroll
    for (int r = 0; r < 4; ++r)
      Zb[(wid * 16 + lg * 4 + r) * ZQS + co * 16 + l15] = pack2(aR[co][r], aI[co][r]);
  __syncthreads();

  // ---- MLP layer 1 (deduped B-frags: frag(kk>=3,nt) = +/- frag(kk-3, nt-+6))
  f32x4 acc[12];
#pragma unroll
  for (int nt = 0; nt < 12; ++nt) {
    float bv = bpk[n * 192 + nt * 16 + l15];
    acc[nt] = { bv, bv, bv, bv };
  }
#pragma unroll
  for (int kk = 0; kk < 6; ++kk) {
    short8 a = afragq(Zb, wid * 16 + l15, kk * 32 + lg * 8);
#pragma unroll
    for (int nt = 0; nt < 12; ++nt) {
      short8 bfr;
      if (kk < 3) bfr = *(const short8*)&WfL[(kk * 12 + nt) * 512 + lane * 8];
      else {
        int nt2 = (nt < 6) ? nt + 6 : nt - 6;
        int4 nb = *(const int4*)&WfL[((kk - 3) * 12 + nt2) * 512 + lane * 8];
        if (nt < 6) { nb.x ^= 0x80008000; nb.y ^= 0x80008000; nb.z ^= 0x80008000; nb.w ^= 0x80008000; }
        bfr = __builtin_bit_cast(short8, nb);
      }
      acc[nt] = MFMA(a, bfr, acc[nt], 0, 0, 0);
    }
  }
  // relu -> own rows of Zq
#pragma unroll
  for (int nt = 0; nt < 6; ++nt)
#pragma unroll
    for (int r = 0; r < 4; ++r)
      Zb[(wid * 16 + lg * 4 + r) * ZQS + nt * 16 + l15] =
          pack2(fmaxf(acc[nt][r], 0.f), fmaxf(acc[nt + 6][r], 0.f));
  __syncthreads();                                  // L1 WfL reads done
  {
    const int4* src = (const int4*)(wf + WF_OFF + (size_t)(8 + n) * (36 * 512));
    for (int idx = t; idx < 2304; idx += 512) ((int4*)WfL)[idx] = src[idx];
  }
#pragma unroll
  for (int nt = 0; nt < 12; ++nt) {
    float bv = bpk[(8 + n) * 192 + nt * 16 + l15];
    acc[nt] = { bv, bv, bv, bv };
  }
  __syncthreads();

  // ---- MLP layer 2
#pragma unroll
  for (int kk = 0; kk < 6; ++kk) {
    short8 a = afragq(Zb, wid * 16 + l15, kk * 32 + lg * 8);
#pragma unroll
    for (int nt = 0; nt < 12; ++nt) {
      short8 bfr;
      if (kk < 3) bfr = *(const short8*)&WfL[(kk * 12 + nt) * 512 + lane * 8];
      else {
        int nt2 = (nt < 6) ? nt + 6 : nt - 6;
        int4 nb = *(const int4*)&WfL[((kk - 3) * 12 + nt2) * 512 + lane * 8];
        if (nt < 6) { nb.x ^= 0x80008000; nb.y ^= 0x80008000; nb.z ^= 0x80008000; nb.w ^= 0x80008000; }
        bfr = __builtin_bit_cast(short8, nb);
      }
      acc[nt] = MFMA(a, bfr, acc[nt], 0, 0, 0);
    }
  }
  __syncthreads();                                  // all L2 Zq reads done

  // ---- softshrink + write as Zc2[ch][ko] (natural ko order)
#pragma unroll
  for (int r = 0; r < 4; ++r) {
    int ko = wid * 16 + lg * 4 + r;
    float kus = (ko >= 64) ? (float)(ko - 128) : (float)ko;
    float k2v = kus * kus + (float)(kv * kv);
    float thr = fmaxf(0.01f * expf(-0.00125f * k2v), 0.0005f);
#pragma unroll
    for (int nt = 0; nt < 6; ++nt) {
      float mr = acc[nt][r], mi = acc[nt + 6][r];
      float mag = sqrtf(mr * mr + mi * mi + 1e-8f);
      float sf = fmaxf(mag - thr, 0.f) / mag;
      Zb[(nt * 16 + l15) * ZCS + ko] = pack2(mr * sf, mi * sf);
    }
  }
  __syncthreads();

  // ---- GEMM-2: inverse H-DFT, write straight to global
#pragma unroll
  for (int co = 0; co < 6; ++co) { aR[co] = {0.f,0.f,0.f,0.f}; aI[co] = {0.f,0.f,0.f,0.f}; }
  dft_gemm<128>(Zb, tm, wid, lane, aR, aI);
#pragma unroll
  for (int co = 0; co < 6; ++co)
#pragma unroll
    for (int r = 0; r < 4; ++r) {
      int rr = wid * 16 + lg * 4 + r;
      Abase[(size_t)rr * (WC * HD) + co * 16 + l15] = pack2(aR[co][r], aI[co][r]);
    }
}

extern "C" void kernel_launch(void* const* d_in, const int* in_sizes, int n_in,
                              void* d_out, int out_size, void* d_ws, size_t ws_size,
                              hipStream_t stream) {
  const float* x  = (const float*)d_in[0];
  const float* w1 = (const float*)d_in[1];
  const float* b1 = (const float*)d_in[2];
  const float* w2 = (const float*)d_in[3];
  const float* b2 = (const float*)d_in[4];
  float* out = (float*)d_out;
  unsigned int* A = (unsigned int*)d_ws;            // 102.2 MB spectral plane

  // baked tables in d_ws right after A (~0.95 MB) — no kernel writes near them
  unsigned short* wf = (unsigned short*)(A + A_UINTS);
  float* bpk = (float*)(wf + WF_END_U16);

  k_prep<<<20, 256, 0, stream>>>(w1, b1, w2, b2, wf, bpk);
  k_fft_w<<<dim3(HH, HD / 64, 4), 256, 0, stream>>>(x, A, wf);
  k_mid<<<dim3(WC, NBLK, 4), 512, 0, stream>>>(A, wf, bpk);
  k_ifft_w<<<dim3(HH, HD / 64, 4), 256, 0, stream>>>(A, x, out, wf);
}